// Round 9
// baseline (267.446 us; speedup 1.0000x reference)
//
#include <hip/hip_runtime.h>
#include <math.h>

// Problem constants (fixed by the reference)
#define G    120     // B*T frames
#define Nn   2000    // nodes per frame
#define Ee   32000   // edges per frame
#define Tt   30
#define Bb   4
#define Fg   128     // GRU hidden
#define QCAP 9216    // CSR capacity per (frame,quadrant); expected 8000, sigma 78
#define TSLOT 48     // transposed-ELL slots/node: slot0=self + up to 47 edges

static __device__ __forceinline__ unsigned short f2bf(float f) {
    unsigned u = __float_as_uint(f);
    u += 0x7fffu + ((u >> 16) & 1u);          // round-to-nearest-even
    return (unsigned short)(u >> 16);
}

// ---------------- fp8 e4m3 encode/decode: HW builtins if available, SW fallback.
#if defined(__has_builtin)
#if __has_builtin(__builtin_amdgcn_cvt_f32_fp8) && __has_builtin(__builtin_amdgcn_cvt_pk_fp8_f32)
#define HW_FP8 1
#endif
#if __has_builtin(__builtin_amdgcn_cvt_pk_f32_fp8)
#define HW_FP8_PK 1
typedef float floatx2 __attribute__((ext_vector_type(2)));
#endif
#endif

static __device__ __forceinline__ unsigned fp8_enc_sw(float x) {
    unsigned s = (__float_as_uint(x) >> 24) & 0x80u;
    float ax = fminf(fabsf(x), 448.f);
    unsigned em;
    if (ax < 0.015625f) {
        em = (unsigned)__float2int_rn(ax * 512.f);
    } else {
        int e = (int)(__float_as_uint(ax) >> 23) - 127;
        float r = ax * __uint_as_float((unsigned)((130 - e) << 23));
        int q = __float2int_rn(r);
        em = (unsigned)(((e + 7) << 3) + (q - 8));
        em = min(em, 126u);
    }
    return s | em;
}
static __device__ __forceinline__ float fp8_dec_sw(unsigned b) {
    unsigned em = b & 0x7fu;
    float mag;
    if (em < 8u) mag = (float)em * 0.001953125f;
    else mag = __uint_as_float((((em >> 3) + 120u) << 23) | ((em & 7u) << 20));
    return (b & 0x80u) ? -mag : mag;
}
static __device__ __forceinline__ unsigned fp8_pack4(float a, float b, float c, float d) {
#ifdef HW_FP8
    int w = __builtin_amdgcn_cvt_pk_fp8_f32(a, b, 0, false);
    w = __builtin_amdgcn_cvt_pk_fp8_f32(c, d, w, true);
    return (unsigned)w;
#else
    return fp8_enc_sw(a) | (fp8_enc_sw(b) << 8) | (fp8_enc_sw(c) << 16) | (fp8_enc_sw(d) << 24);
#endif
}
static __device__ __forceinline__ void fp8x4_dec(unsigned dw, float* o) {
#ifdef HW_FP8_PK
    floatx2 lo = __builtin_amdgcn_cvt_pk_f32_fp8((int)dw, false);
    floatx2 hi = __builtin_amdgcn_cvt_pk_f32_fp8((int)dw, true);
    o[0] = lo[0]; o[1] = lo[1]; o[2] = hi[0]; o[3] = hi[1];
#else
    o[0] = fp8_dec_sw(dw & 0xffu);
    o[1] = fp8_dec_sw((dw >> 8) & 0xffu);
    o[2] = fp8_dec_sw((dw >> 16) & 0xffu);
    o[3] = fp8_dec_sw((dw >> 24) & 0xffu);
#endif
}

// ---- K0 (new, R9): per-frame degree histogram -> dis, + emb zero.
// Removes the 4x-redundant full-frame histogram from k_build (was 480 blocks
// each histogramming all 32k edges; now 120 blocks do it once).
__global__ void __launch_bounds__(1024, 1)
k_deg(const int* __restrict__ ei, float* __restrict__ dis, float* __restrict__ emb) {
    __shared__ int hist[Nn];
    int g = blockIdx.x;               // 0..119
    int tid = threadIdx.x;
    for (int idx = tid; idx < Nn; idx += 1024) hist[idx] = 0;
    if (tid < 64) emb[g * 64 + tid] = 0.f;
    __syncthreads();
    const int* dstp = ei + (size_t)g * 2 * Ee + Ee;
    for (int it = tid; it < Ee / 4; it += 1024) {
        int4 d = reinterpret_cast<const int4*>(dstp)[it];
        atomicAdd(&hist[d.x], 1);
        atomicAdd(&hist[d.y], 1);
        atomicAdd(&hist[d.z], 1);
        atomicAdd(&hist[d.w], 1);
    }
    __syncthreads();
    for (int idx = tid; idx < Nn; idx += 1024)
        dis[(size_t)g * Nn + idx] = rsqrtf((float)hist[idx] + 1.0f);
}

// ---- K1: per-quadrant build (R9: histogram atomics FILTERED to own quadrant,
// 1/4 the LDS-atomic work; dis staged from k_deg's global output; dead cntA
// stream removed).
__global__ void __launch_bounds__(1024, 1)
k_build(const int* __restrict__ ei, const float* __restrict__ dis,
        int* __restrict__ startA, int* __restrict__ csr,
        unsigned* __restrict__ ellT, int* __restrict__ cntS,
        int* __restrict__ ordS) {
    __shared__ int   histq[500];      // own-quadrant counts, then cursor
    __shared__ float disl[Nn];
    __shared__ int   ws[512];
    __shared__ int   csr_l[QCAP];
    __shared__ int   cntQ[500];
    __shared__ int   exQ[500];
    __shared__ int   nodeAt[500];     // sorted position -> local node idx
    __shared__ int   dh[64];          // degree histogram, then cursor
    __shared__ int   db[64];          // degree-bin exclusive base
    __shared__ int   ovfS;
    int i = blockIdx.x;               // 0..479
    int xcd = i & 7;
    int j = i >> 3;                   // 0..59
    int f15 = j >> 2;                 // 0..14
    int q = j & 3;
    int g = xcd * 15 + f15;
    int gq = g * 4 + q;
    int lo = q * 500;
    int tid = threadIdx.x;
    // P1: init + stage disl from k_deg's output (coalesced 2000 floats)
    for (int idx = tid; idx < Nn; idx += 1024) disl[idx] = dis[(size_t)g * Nn + idx];
    if (tid < 500) histq[tid] = 0;
    if (tid < 64) dh[tid] = 0;
    if (tid == 0) ovfS = 0;
    __syncthreads();
    // P2: own-quadrant histogram of destinations (1/4 the atomics of full)
    const int* srcp = ei + (size_t)g * 2 * Ee;
    const int* dstp = srcp + Ee;
    for (int it = tid; it < Ee / 4; it += 1024) {
        int4 d = reinterpret_cast<const int4*>(dstp)[it];
        if ((unsigned)(d.x - lo) < 500u) atomicAdd(&histq[d.x - lo], 1);
        if ((unsigned)(d.y - lo) < 500u) atomicAdd(&histq[d.y - lo], 1);
        if ((unsigned)(d.z - lo) < 500u) atomicAdd(&histq[d.z - lo], 1);
        if ((unsigned)(d.w - lo) < 500u) atomicAdd(&histq[d.w - lo], 1);
    }
    __syncthreads();
    // P3a: own-quadrant counts for scan
    int cnt = 0;
    if (tid < 512) ws[tid] = (tid < 500) ? histq[tid] : 0;
    if (tid < 500) cnt = histq[tid];
    __syncthreads();
    // P3b: inclusive scan over 512
    for (int off = 1; off < 512; off <<= 1) {
        int v = 0;
        if (tid < 512 && tid >= off) v = ws[tid - off];
        __syncthreads();
        if (tid < 512) ws[tid] += v;
        __syncthreads();
    }
    int ex = 0;
    if (tid < 500) ex = ws[tid] - cnt;
    // P3c: cursor + per-node arrays + degree histogram
    if (tid < 500) {
        histq[tid] = ex;                           // cursor for P4
        cntQ[tid] = cnt;
        exQ[tid] = ex;
        if (cnt > TSLOT - 1) atomicMax(&ovfS, 1);
        atomicAdd(&dh[min(cnt, 63)], 1);
    }
    __syncthreads();
    // P3d: exclusive scan of degree bins (serial, 64 elems), then cursor=base
    if (tid == 0) {
        int s = 0;
        for (int b = 0; b < 64; ++b) { db[b] = s; s += dh[b]; }
    }
    __syncthreads();
    if (tid < 64) dh[tid] = db[tid];               // cursor per bin
    __syncthreads();
    // P3e: assign sorted positions
    if (tid < 500) {
        int p = atomicAdd(&dh[min(cnt, 63)], 1);
        nodeAt[p] = tid;
    }
    // P4: fill own-quadrant CSR in LDS
    for (int it = tid; it < Ee / 4; it += 1024) {
        int4 d = reinterpret_cast<const int4*>(dstp)[it];
        int4 s = reinterpret_cast<const int4*>(srcp)[it];
        if ((unsigned)(d.x - lo) < 500u) { int p = atomicAdd(&histq[d.x - lo], 1); if (p < QCAP) csr_l[p] = s.x; }
        if ((unsigned)(d.y - lo) < 500u) { int p = atomicAdd(&histq[d.y - lo], 1); if (p < QCAP) csr_l[p] = s.y; }
        if ((unsigned)(d.z - lo) < 500u) { int p = atomicAdd(&histq[d.z - lo], 1); if (p < QCAP) csr_l[p] = s.z; }
        if ((unsigned)(d.w - lo) < 500u) { int p = atomicAdd(&histq[d.w - lo], 1); if (p < QCAP) csr_l[p] = s.w; }
    }
    __syncthreads();
    // P5: per-node outputs. Thread t emits SORTED position t (node nodeAt[t]):
    // ELL stores coalesced across t; loop trip wave-uniform (sorted degrees).
    if (tid < 500) {
        int n_own = lo + tid;
        size_t gn_own = (size_t)g * Nn + n_own;
        startA[gn_own] = gq * QCAP + ex;
        // sorted emit
        int sl = nodeAt[tid];                      // local node idx at position tid
        int n2 = lo + sl;
        int cnt2 = cntQ[sl];
        int ex2 = exQ[sl];
        int c = q * 500 + tid;                     // frame-global sorted column
        size_t gc = (size_t)g * Nn + c;
        cntS[gc] = cnt2;
        ordS[gc] = n2;
        float dn2 = disl[n2];
        unsigned* et = ellT + (size_t)g * TSLOT * Nn + c;
        et[0] = (unsigned)n2 | ((unsigned)f2bf(dn2 * dn2) << 16);
        int m2 = min(cnt2, TSLOT - 1);
        for (int e = 0; e < m2; ++e) {
            int s = csr_l[ex2 + e];
            et[(size_t)(e + 1) * Nn] = (unsigned)s | ((unsigned)f2bf(disl[s] * dn2) << 16);
        }
    }
    __syncthreads();
    // P6: global CSR write only if some node overflowed (exact fallback path)
    if (ovfS) {
        int total = ws[511];
        int* cg = csr + (size_t)gq * QCAP;
        for (int it = tid; it < total; it += 1024) cg[it] = csr_l[it];
    }
}

// ---- K2: fused per-lane pipeline — FROZEN at the R3 structure (best measured
// 62-86 µs, VALU-work invariant ~30 µs; see R8 post-mortem). One thread per
// node, grid 960, batched 8-wide et gather, global x4 reads, block-uniform
// weight loads -> s_load path.
__global__ void __launch_bounds__(256)
k_fused(const float* __restrict__ x, const unsigned* __restrict__ ellT,
        const int* __restrict__ cntS, const int* __restrict__ ordS,
        const int* __restrict__ startA, const int* __restrict__ csr,
        const float* __restrict__ dis,
        const float* __restrict__ W1, const float* __restrict__ b1,
        const float* __restrict__ W2, unsigned char* __restrict__ t2f) {
    int i = blockIdx.x;                 // 960 = 8 xcd * 15 frames * 8 pos-blocks
    int xcd = i & 7;
    int j = i >> 3;                     // 0..119
    int g = xcd * 15 + (j >> 3);
    int blk = j & 7;
    int p = blk * 256 + threadIdx.x;    // sorted position
    bool valid = (p < Nn);
    size_t gp = (size_t)g * Nn + (valid ? p : 0);
    int n = valid ? ordS[gp] : 0;
    int cnt = valid ? cntS[gp] : 0;
    int myc = valid ? (min(cnt, TSLOT - 1) + 1) : 0;
    // phase 0: aggregate raw x (8-dim) into registers via sorted ELL, batch 8
    float aX[8];
#pragma unroll
    for (int k = 0; k < 8; ++k) aX[k] = 0.f;
    {
        const unsigned* et = ellT + (size_t)g * TSLOT * Nn + (valid ? p : 0);
        const float4* x4 = reinterpret_cast<const float4*>(x + (size_t)g * Nn * 8);
        for (int e0 = 0; e0 < TSLOT; e0 += 8) {
            if (!__any(e0 < myc)) break;
            unsigned ub[8];
#pragma unroll
            for (int k = 0; k < 8; ++k)
                ub[k] = (e0 + k < myc) ? et[(size_t)(e0 + k) * Nn] : 0u;
#pragma unroll
            for (int k = 0; k < 8; ++k) {
                if (e0 + k < myc) {
                    float w = __uint_as_float(ub[k] & 0xffff0000u);
                    int s = ub[k] & 0xffffu;
                    float4 r0 = x4[s * 2], r1 = x4[s * 2 + 1];
                    aX[0] += r0.x * w; aX[1] += r0.y * w; aX[2] += r0.z * w; aX[3] += r0.w * w;
                    aX[4] += r1.x * w; aX[5] += r1.y * w; aX[6] += r1.z * w; aX[7] += r1.w * w;
                }
            }
        }
        if (cnt > TSLOT - 1) {          // rare overflow (deg > 47)
            size_t gn = (size_t)g * Nn + n;
            float dn = dis[gn];
            int start = startA[gn];
            const float* dsg = dis + (size_t)g * Nn;
            for (int e = TSLOT - 1; e < cnt; ++e) {
                int s = csr[start + e];
                float w = dsg[s] * dn;
                float4 r0 = x4[s * 2], r1 = x4[s * 2 + 1];
                aX[0] += r0.x * w; aX[1] += r0.y * w; aX[2] += r0.z * w; aX[3] += r0.w * w;
                aX[4] += r1.x * w; aX[5] += r1.y * w; aX[6] += r1.z * w; aX[7] += r1.w * w;
            }
        }
    }
    // phase 1: h1 = relu(aX @ W1 + b1), W1/b1 uniform scalar loads, full unroll
    float h1r[64];
    {
        const float4* b14 = reinterpret_cast<const float4*>(b1);
#pragma unroll
        for (int f4 = 0; f4 < 16; ++f4) {
            float4 b = b14[f4];
            h1r[4 * f4 + 0] = b.x; h1r[4 * f4 + 1] = b.y;
            h1r[4 * f4 + 2] = b.z; h1r[4 * f4 + 3] = b.w;
        }
        const float4* W14 = reinterpret_cast<const float4*>(W1);
#pragma unroll
        for (int k = 0; k < 8; ++k) {
            float hk = aX[k];
#pragma unroll
            for (int f4 = 0; f4 < 16; ++f4) {
                float4 w = W14[k * 16 + f4];
                h1r[4 * f4 + 0] += hk * w.x; h1r[4 * f4 + 1] += hk * w.y;
                h1r[4 * f4 + 2] += hk * w.z; h1r[4 * f4 + 3] += hk * w.w;
            }
        }
#pragma unroll
        for (int f = 0; f < 64; ++f) h1r[f] = fmaxf(h1r[f], 0.f);
    }
    // phase 2: t2 = h1 @ W2 (fp8 out), two 32-feature halves (caps live VGPRs),
    // FULL unroll everywhere -> constant indices -> no scratch. hf is a LOOP
    // variable (block-uniform W2 addresses -> s_load path; R4 lesson).
    uint4 oh[2][2];
    {
        const float4* W24 = reinterpret_cast<const float4*>(W2);
#pragma unroll
        for (int hf = 0; hf < 2; ++hf) {
            float acch[32];
#pragma unroll
            for (int f = 0; f < 32; ++f) acch[f] = 0.f;
#pragma unroll
            for (int k = 0; k < 64; ++k) {
                float hk = h1r[k];
#pragma unroll
                for (int f4 = 0; f4 < 8; ++f4) {
                    float4 w = W24[k * 16 + hf * 8 + f4];
                    acch[4 * f4 + 0] += hk * w.x; acch[4 * f4 + 1] += hk * w.y;
                    acch[4 * f4 + 2] += hk * w.z; acch[4 * f4 + 3] += hk * w.w;
                }
            }
            oh[hf][0].x = fp8_pack4(acch[0],  acch[1],  acch[2],  acch[3]);
            oh[hf][0].y = fp8_pack4(acch[4],  acch[5],  acch[6],  acch[7]);
            oh[hf][0].z = fp8_pack4(acch[8],  acch[9],  acch[10], acch[11]);
            oh[hf][0].w = fp8_pack4(acch[12], acch[13], acch[14], acch[15]);
            oh[hf][1].x = fp8_pack4(acch[16], acch[17], acch[18], acch[19]);
            oh[hf][1].y = fp8_pack4(acch[20], acch[21], acch[22], acch[23]);
            oh[hf][1].z = fp8_pack4(acch[24], acch[25], acch[26], acch[27]);
            oh[hf][1].w = fp8_pack4(acch[28], acch[29], acch[30], acch[31]);
        }
    }
    if (valid) {
        uint4* op = reinterpret_cast<uint4*>(t2f + ((size_t)g * Nn + n) * 64);
        op[0] = oh[0][0]; op[1] = oh[0][1]; op[2] = oh[1][0]; op[3] = oh[1][1];
    }
}

// ---- K3: LDS-staged aggregation of t2 (fp8) + relu + mean-pool.
// R9: 1-deep et prefetch — issue et[e+1] before the ~112-inst edge body so the
// ~300cy L2 latency hides under compute (the serial dependent chain was the
// estimated stall source; +1 VGPR).
__global__ void __launch_bounds__(1024, 1)
k_aggF(const unsigned char* __restrict__ t2f, const unsigned* __restrict__ ellT,
       const int* __restrict__ cntS, const int* __restrict__ ordS,
       const int* __restrict__ startA, const int* __restrict__ csr,
       const float* __restrict__ dis, const float* __restrict__ bias,
       float* __restrict__ emb) {
    __shared__ uint4 stage[Nn * 5];     // 160,000 B; row s at stage[s*5 .. s*5+3]
    int i = blockIdx.x;                 // 240 = 8 xcd * 15 frames * 2 halves
    int xcd = i & 7;
    int j = i >> 3;                     // 0..29
    int g = xcd * 15 + (j >> 1);
    int half = j & 1;
    int tid = threadIdx.x;              // 0..1023
    int w = tid >> 6, lane = tid & 63;
    // stage entire frame t2 (fp8) into LDS with padded stride
    {
        const uint4* src = reinterpret_cast<const uint4*>(t2f + (size_t)g * Nn * 64);
        for (int it = tid; it < Nn * 4; it += 1024)
            stage[(it >> 2) * 5 + (it & 3)] = src[it];
    }
    __syncthreads();
#define ROWFMA(dw, base) { float o_[4]; fp8x4_dec(dw, o_); \
    acc[base + 0] += o_[0] * wt; acc[base + 1] += o_[1] * wt; \
    acc[base + 2] += o_[2] * wt; acc[base + 3] += o_[3] * wt; }
#define EDGEFMA(s, wt) { \
    uint4 r0 = stage[(s) * 5], r1 = stage[(s) * 5 + 1]; \
    uint4 r2 = stage[(s) * 5 + 2], r3 = stage[(s) * 5 + 3]; \
    ROWFMA(r0.x, 0)  ROWFMA(r0.y, 4)  ROWFMA(r0.z, 8)  ROWFMA(r0.w, 12) \
    ROWFMA(r1.x, 16) ROWFMA(r1.y, 20) ROWFMA(r1.z, 24) ROWFMA(r1.w, 28) \
    ROWFMA(r2.x, 32) ROWFMA(r2.y, 36) ROWFMA(r2.z, 40) ROWFMA(r2.w, 44) \
    ROWFMA(r3.x, 48) ROWFMA(r3.y, 52) ROWFMA(r3.z, 56) ROWFMA(r3.w, 60) }
    int po = w * 64 + lane;             // 0..1023
    int p = half * 1000 + po;           // sorted position
    bool valid = (po < 1000);
    size_t gp = (size_t)g * Nn + (valid ? p : 0);
    int cnt = valid ? cntS[gp] : 0;
    int myc = valid ? (min(cnt, TSLOT - 1) + 1) : 0;
    float acc[64];
#pragma unroll
    for (int k = 0; k < 64; ++k) acc[k] = 0.f;
    const unsigned* et = ellT + (size_t)g * TSLOT * Nn + (valid ? p : 0);
    unsigned u_cur = (0 < myc) ? et[0] : 0u;
    for (int e = 0; e < TSLOT; ++e) {
        if (!__any(e < myc)) break;
        unsigned u_nxt = ((e + 1) < TSLOT && (e + 1) < myc)
                             ? et[(size_t)(e + 1) * Nn] : 0u;   // issued early
        if (e < myc) {
            float wt = __uint_as_float(u_cur & 0xffff0000u);
            int s = u_cur & 0xffffu;
            EDGEFMA(s, wt)
        }
        u_cur = u_nxt;
    }
    if (cnt > TSLOT - 1) {              // rare overflow (deg > 47)
        int n = ordS[gp];
        size_t gn = (size_t)g * Nn + n;
        float dn = dis[gn];
        int start = startA[gn];
        const float* dsg = dis + (size_t)g * Nn;
        for (int e = TSLOT - 1; e < cnt; ++e) {
            int s = csr[start + e];
            float wt = dsg[s] * dn;
            EDGEFMA(s, wt)
        }
    }
#undef EDGEFMA
#undef ROWFMA
    // bias + relu + per-feature butterfly pool over the wave's 64 positions
    float pool = 0.f;
#pragma unroll
    for (int k = 0; k < 64; ++k) {
        float v = valid ? fmaxf(acc[k] + bias[k], 0.f) : 0.f;
        v += __shfl_xor(v, 1);  v += __shfl_xor(v, 2);  v += __shfl_xor(v, 4);
        v += __shfl_xor(v, 8);  v += __shfl_xor(v, 16); v += __shfl_xor(v, 32);
        if (lane == k) pool = v;
    }
    atomicAdd(&emb[g * 64 + lane], pool * (1.0f / Nn));
}

// ---- K5: sequential GRU over T with FUSED gi precompute (k_gi removed;
// R8 evidence: fusion worth ~20 µs on the non-k_fused total).
__global__ void __launch_bounds__(768, 1)
k_gru_seq(const float* __restrict__ emb, const float* __restrict__ W_ih,
          const float* __restrict__ b_ih, const float* __restrict__ W_hh,
          const float* __restrict__ b_hh, const float* __restrict__ fc_w,
          const float* __restrict__ fc_b, float* __restrict__ out) {
    __shared__ float h[Fg];
    __shared__ float part[768];
    __shared__ float embs[Tt][64];       // 7.7 KB
    __shared__ float pgi[Tt][768];       // 92 KB: gi half-dots
    int b = blockIdx.x;                  // batch
    int tid = threadIdx.x;               // 0..767
    int row = tid >> 1;                  // gate-row 0..383
    int half = tid & 1;                  // which 64-slice of k
    float w[64];
    const float* wr = W_hh + (size_t)row * Fg + half * 64;
#pragma unroll
    for (int i = 0; i < 64; ++i) w[i] = wr[i];
    float wih[32];
    const float* wir = W_ih + (size_t)row * 64 + half * 32;
#pragma unroll
    for (int i = 0; i < 32; ++i) wih[i] = wir[i];
    // stage emb rows for this batch
    for (int it = tid; it < Tt * 64; it += 768)
        embs[it >> 6][it & 63] = emb[((size_t)b * Tt) * 64 + it];
    if (tid < Fg) h[tid] = 0.f;
    __syncthreads();
    // precompute gi half-dots for all timesteps (independent per thread)
    for (int t = 0; t < Tt; ++t) {
        const float* e = &embs[t][half * 32];
        float a0 = 0.f, a1 = 0.f, a2 = 0.f, a3 = 0.f;
#pragma unroll
        for (int i = 0; i < 8; ++i) {
            a0 += wih[4 * i + 0] * e[4 * i + 0];
            a1 += wih[4 * i + 1] * e[4 * i + 1];
            a2 += wih[4 * i + 2] * e[4 * i + 2];
            a3 += wih[4 * i + 3] * e[4 * i + 3];
        }
        pgi[t][tid] = (a0 + a1) + (a2 + a3);
    }
    __syncthreads();
    for (int t = 0; t < Tt; ++t) {
        const float* hh = &h[half * 64];
        float a0 = 0.f, a1 = 0.f, a2 = 0.f, a3 = 0.f;
#pragma unroll
        for (int i = 0; i < 16; ++i) {
            a0 += w[4 * i + 0] * hh[4 * i + 0];
            a1 += w[4 * i + 1] * hh[4 * i + 1];
            a2 += w[4 * i + 2] * hh[4 * i + 2];
            a3 += w[4 * i + 3] * hh[4 * i + 3];
        }
        part[tid] = (a0 + a1) + (a2 + a3);
        __syncthreads();
        if (tid < Fg) {
            int j = tid;
            float hr = b_hh[j]       + part[2 * j]           + part[2 * j + 1];
            float hz = b_hh[128 + j] + part[2 * (128 + j)]   + part[2 * (128 + j) + 1];
            float hn = b_hh[256 + j] + part[2 * (256 + j)]   + part[2 * (256 + j) + 1];
            float gr = b_ih[j]       + pgi[t][2 * j]         + pgi[t][2 * j + 1];
            float gz = b_ih[128 + j] + pgi[t][2 * (128 + j)] + pgi[t][2 * (128 + j) + 1];
            float gn = b_ih[256 + j] + pgi[t][2 * (256 + j)] + pgi[t][2 * (256 + j) + 1];
            float r  = 1.f / (1.f + expf(-(gr + hr)));
            float z  = 1.f / (1.f + expf(-(gz + hz)));
            float nn = tanhf(gn + r * hn);
            h[j] = (1.f - z) * nn + z * h[j];
        }
        __syncthreads();
    }
    if (tid < 2) {
        float acc = fc_b[tid];
        for (int k = 0; k < Fg; ++k) acc += fc_w[tid * Fg + k] * h[k];
        out[b * 2 + tid] = acc;
    }
}

// ----------------------------------------------------------------- launcher
extern "C" void kernel_launch(void* const* d_in, const int* in_sizes, int n_in,
                              void* d_out, int out_size, void* d_ws, size_t ws_size,
                              hipStream_t stream) {
    const float* x     = (const float*)d_in[0];
    const int*   ei    = (const int*)  d_in[1];
    const float* W1    = (const float*)d_in[2];
    const float* b1    = (const float*)d_in[3];
    const float* W2    = (const float*)d_in[4];
    const float* b2    = (const float*)d_in[5];
    const float* W_ih  = (const float*)d_in[6];
    const float* W_hh  = (const float*)d_in[7];
    const float* b_ih  = (const float*)d_in[8];
    const float* b_hh  = (const float*)d_in[9];
    const float* fc_w  = (const float*)d_in[10];
    const float* fc_b  = (const float*)d_in[11];
    float* out = (float*)d_out;

    char* ws = (char*)d_ws;
    size_t off = 0;
    auto alloc = [&](size_t bytes) -> void* {
        void* p = ws + off;
        off = (off + bytes + 255) & ~(size_t)255;
        return p;
    };
    float*    dis    = (float*)   alloc((size_t)G * Nn * 4);
    int*      startA = (int*)     alloc((size_t)G * Nn * 4);
    int*      cntS   = (int*)     alloc((size_t)G * Nn * 4);
    int*      ordS   = (int*)     alloc((size_t)G * Nn * 4);
    int*      csr    = (int*)     alloc((size_t)G * 4 * QCAP * 4);
    unsigned* ellT   = (unsigned*)alloc((size_t)G * TSLOT * Nn * 4);
    unsigned char* t2f = (unsigned char*)alloc((size_t)G * Nn * 64);
    float*    emb    = (float*)   alloc((size_t)G * 64 * 4);
    (void)ws_size; (void)in_sizes; (void)n_in; (void)out_size;

    hipLaunchKernelGGL(k_deg,     dim3(G), dim3(1024), 0, stream, ei, dis, emb);
    hipLaunchKernelGGL(k_build,   dim3(480), dim3(1024), 0, stream, ei, dis, startA, csr, ellT, cntS, ordS);
    hipLaunchKernelGGL(k_fused,   dim3(960), dim3(256), 0, stream, x, ellT, cntS, ordS, startA, csr, dis, W1, b1, W2, t2f);
    hipLaunchKernelGGL(k_aggF,    dim3(240), dim3(1024), 0, stream, t2f, ellT, cntS, ordS, startA, csr, dis, b2, emb);
    hipLaunchKernelGGL(k_gru_seq, dim3(Bb), dim3(768), 0, stream, emb, W_ih, b_ih, W_hh, b_hh, fc_w, fc_b, out);
}

// Round 11
// 266.024 us; speedup vs baseline: 1.0053x; 1.0053x over previous
//
#include <hip/hip_runtime.h>
#include <math.h>

// Problem constants (fixed by the reference)
#define G    120     // B*T frames
#define Nn   2000    // nodes per frame
#define Ee   32000   // edges per frame
#define Tt   30
#define Bb   4
#define Fg   128     // GRU hidden
#define QCAP 9216    // global CSR spill capacity per (frame,quadrant-slot); 4*QCAP/frame
#define TSLOT 48     // transposed-ELL slots/node: slot0=self + up to 47 edges

static __device__ __forceinline__ unsigned short f2bf(float f) {
    unsigned u = __float_as_uint(f);
    u += 0x7fffu + ((u >> 16) & 1u);          // round-to-nearest-even
    return (unsigned short)(u >> 16);
}

// ---------------- fp8 e4m3 encode/decode: HW builtins if available, SW fallback.
#if defined(__has_builtin)
#if __has_builtin(__builtin_amdgcn_cvt_f32_fp8) && __has_builtin(__builtin_amdgcn_cvt_pk_fp8_f32)
#define HW_FP8 1
#endif
#if __has_builtin(__builtin_amdgcn_cvt_pk_f32_fp8)
#define HW_FP8_PK 1
typedef float floatx2 __attribute__((ext_vector_type(2)));
#endif
#endif

static __device__ __forceinline__ unsigned fp8_enc_sw(float x) {
    unsigned s = (__float_as_uint(x) >> 24) & 0x80u;
    float ax = fminf(fabsf(x), 448.f);
    unsigned em;
    if (ax < 0.015625f) {
        em = (unsigned)__float2int_rn(ax * 512.f);
    } else {
        int e = (int)(__float_as_uint(ax) >> 23) - 127;
        float r = ax * __uint_as_float((unsigned)((130 - e) << 23));
        int q = __float2int_rn(r);
        em = (unsigned)(((e + 7) << 3) + (q - 8));
        em = min(em, 126u);
    }
    return s | em;
}
static __device__ __forceinline__ float fp8_dec_sw(unsigned b) {
    unsigned em = b & 0x7fu;
    float mag;
    if (em < 8u) mag = (float)em * 0.001953125f;
    else mag = __uint_as_float((((em >> 3) + 120u) << 23) | ((em & 7u) << 20));
    return (b & 0x80u) ? -mag : mag;
}
static __device__ __forceinline__ unsigned fp8_pack4(float a, float b, float c, float d) {
#ifdef HW_FP8
    int w = __builtin_amdgcn_cvt_pk_fp8_f32(a, b, 0, false);
    w = __builtin_amdgcn_cvt_pk_fp8_f32(c, d, w, true);
    return (unsigned)w;
#else
    return fp8_enc_sw(a) | (fp8_enc_sw(b) << 8) | (fp8_enc_sw(c) << 16) | (fp8_enc_sw(d) << 24);
#endif
}
static __device__ __forceinline__ void fp8x4_dec(unsigned dw, float* o) {
#ifdef HW_FP8_PK
    floatx2 lo = __builtin_amdgcn_cvt_pk_f32_fp8((int)dw, false);
    floatx2 hi = __builtin_amdgcn_cvt_pk_f32_fp8((int)dw, true);
    o[0] = lo[0]; o[1] = lo[1]; o[2] = hi[0]; o[3] = hi[1];
#else
    o[0] = fp8_dec_sw(dw & 0xffu);
    o[1] = fp8_dec_sw((dw >> 8) & 0xffu);
    o[2] = fp8_dec_sw((dw >> 16) & 0xffu);
    o[3] = fp8_dec_sw((dw >> 24) & 0xffu);
#endif
}

// ---- K1 (R10): WHOLE-FRAME build, 1 block per frame. vs the 4-blocks/frame
// version: edge list scanned 2x not 8x, histogram once not 4x, P5 all-active,
// k_deg kernel eliminated. CSR in LDS is exactly Ee ints (totals are exact ->
// no in-LDS overflow possible). LDS = 128K(csr)+4x8K+bins = 160.5KB (fits).
__global__ void __launch_bounds__(1024, 1)
k_build(const int* __restrict__ ei, float* __restrict__ dis,
        int* __restrict__ startA, int* __restrict__ csr,
        unsigned* __restrict__ ellT, int* __restrict__ cntS,
        int* __restrict__ ordS, float* __restrict__ emb) {
    __shared__ int   csr_l[Ee];       // 128,000 B — whole-frame CSR
    __shared__ int   hist[Nn];        // counts -> inclusive scan -> cursor
    __shared__ int   cntL[Nn];
    __shared__ int   nodeAt[Nn];      // sorted position -> node
    __shared__ float disl[Nn];
    __shared__ int   dh[64];          // degree histogram, then cursor
    __shared__ int   db[64];          // degree-bin exclusive base
    __shared__ int   ovfS;
    int g = blockIdx.x;               // 0..119
    int tid = threadIdx.x;
    // P1: init
    for (int idx = tid; idx < Nn; idx += 1024) hist[idx] = 0;
    if (tid < 64) dh[tid] = 0;
    if (tid == 0) ovfS = 0;
    if (tid < 64) emb[g * 64 + tid] = 0.f;
    __syncthreads();
    // P2: full-frame histogram of destinations (ONCE per frame)
    const int* srcp = ei + (size_t)g * 2 * Ee;
    const int* dstp = srcp + Ee;
    for (int it = tid; it < Ee / 4; it += 1024) {
        int4 d = reinterpret_cast<const int4*>(dstp)[it];
        atomicAdd(&hist[d.x], 1);
        atomicAdd(&hist[d.y], 1);
        atomicAdd(&hist[d.z], 1);
        atomicAdd(&hist[d.w], 1);
    }
    __syncthreads();
    // P3a: cnt snapshot, dis (LDS + global), degree bins, overflow flag
    for (int idx = tid; idx < Nn; idx += 1024) {
        int c = hist[idx];
        cntL[idx] = c;
        float dv = rsqrtf((float)c + 1.0f);
        disl[idx] = dv;
        dis[(size_t)g * Nn + idx] = dv;
        atomicAdd(&dh[min(c, 63)], 1);
        if (c > TSLOT - 1) atomicMax(&ovfS, 1);
    }
    __syncthreads();
    // P3b: in-place inclusive Hillis-Steele scan of hist over Nn=2000
    // (11 rounds, 2 elements per thread: idx=tid and idx=tid+1024;
    //  all reads precede the mid-round barrier, writes follow it)
    for (int off = 1; off < Nn; off <<= 1) {
        int i1 = tid + 1024;
        int v0 = (tid >= off) ? hist[tid - off] : 0;
        int v1 = (i1 < Nn && i1 >= off) ? hist[i1 - off] : 0;
        __syncthreads();
        hist[tid] += v0;
        if (i1 < Nn) hist[i1] += v1;
        __syncthreads();
    }
    // P3c: degree-bin exclusive scan (serial, 64 elems), then cursor=base
    if (tid == 0) {
        int s = 0;
        for (int b = 0; b < 64; ++b) { db[b] = s; s += dh[b]; }
    }
    __syncthreads();
    if (tid < 64) dh[tid] = db[tid];
    __syncthreads();
    // P3d: sorted-position assignment; convert hist from inclusive to cursor(=ex)
    for (int idx = tid; idx < Nn; idx += 1024) {
        int p = atomicAdd(&dh[min(cntL[idx], 63)], 1);
        nodeAt[p] = idx;
        hist[idx] -= cntL[idx];       // cursor = exclusive prefix
    }
    __syncthreads();
    // P4: fill whole-frame CSR (cursor partitions [0,Ee) exactly; no OOB)
    for (int it = tid; it < Ee / 4; it += 1024) {
        int4 d = reinterpret_cast<const int4*>(dstp)[it];
        int4 s = reinterpret_cast<const int4*>(srcp)[it];
        csr_l[atomicAdd(&hist[d.x], 1)] = s.x;
        csr_l[atomicAdd(&hist[d.y], 1)] = s.y;
        csr_l[atomicAdd(&hist[d.z], 1)] = s.z;
        csr_l[atomicAdd(&hist[d.w], 1)] = s.w;
    }
    __syncthreads();
    // P5: emit per sorted column c (all 1024 threads active, 2 columns each).
    // After P4, hist[n] = ex(n)+cnt(n), so ex = hist - cnt.
    for (int c = tid; c < Nn; c += 1024) {
        int n2 = nodeAt[c];
        int cnt2 = cntL[n2];
        int ex2 = hist[n2] - cnt2;
        size_t gc = (size_t)g * Nn + c;
        cntS[gc] = cnt2;
        ordS[gc] = n2;
        startA[(size_t)g * Nn + n2] = g * 4 * QCAP + ex2;
        float dn2 = disl[n2];
        unsigned* et = ellT + (size_t)g * TSLOT * Nn + c;
        et[0] = (unsigned)n2 | ((unsigned)f2bf(dn2 * dn2) << 16);
        int m2 = min(cnt2, TSLOT - 1);
        for (int e = 0; e < m2; ++e) {
            int s = csr_l[ex2 + e];
            et[(size_t)(e + 1) * Nn] = (unsigned)s | ((unsigned)f2bf(disl[s] * dn2) << 16);
        }
    }
    __syncthreads();
    // P6: global CSR spill only if some node overflowed (deg > 47)
    if (ovfS) {
        int* cg = csr + (size_t)g * 4 * QCAP;
        for (int it = tid; it < Ee; it += 1024) cg[it] = csr_l[it];
    }
}

// ---- K2: fused per-lane pipeline — FROZEN at the R3 structure (best measured
// 62-86 µs, VALU-work invariant ~30 µs; see R8 post-mortem). One thread per
// node, grid 960, batched 8-wide et gather, global x4 reads, block-uniform
// weight loads -> s_load path.
__global__ void __launch_bounds__(256)
k_fused(const float* __restrict__ x, const unsigned* __restrict__ ellT,
        const int* __restrict__ cntS, const int* __restrict__ ordS,
        const int* __restrict__ startA, const int* __restrict__ csr,
        const float* __restrict__ dis,
        const float* __restrict__ W1, const float* __restrict__ b1,
        const float* __restrict__ W2, unsigned char* __restrict__ t2f) {
    int i = blockIdx.x;                 // 960 = 8 xcd * 15 frames * 8 pos-blocks
    int xcd = i & 7;
    int j = i >> 3;                     // 0..119
    int g = xcd * 15 + (j >> 3);
    int blk = j & 7;
    int p = blk * 256 + threadIdx.x;    // sorted position
    bool valid = (p < Nn);
    size_t gp = (size_t)g * Nn + (valid ? p : 0);
    int n = valid ? ordS[gp] : 0;
    int cnt = valid ? cntS[gp] : 0;
    int myc = valid ? (min(cnt, TSLOT - 1) + 1) : 0;
    // phase 0: aggregate raw x (8-dim) into registers via sorted ELL, batch 8
    float aX[8];
#pragma unroll
    for (int k = 0; k < 8; ++k) aX[k] = 0.f;
    {
        const unsigned* et = ellT + (size_t)g * TSLOT * Nn + (valid ? p : 0);
        const float4* x4 = reinterpret_cast<const float4*>(x + (size_t)g * Nn * 8);
        for (int e0 = 0; e0 < TSLOT; e0 += 8) {
            if (!__any(e0 < myc)) break;
            unsigned ub[8];
#pragma unroll
            for (int k = 0; k < 8; ++k)
                ub[k] = (e0 + k < myc) ? et[(size_t)(e0 + k) * Nn] : 0u;
#pragma unroll
            for (int k = 0; k < 8; ++k) {
                if (e0 + k < myc) {
                    float w = __uint_as_float(ub[k] & 0xffff0000u);
                    int s = ub[k] & 0xffffu;
                    float4 r0 = x4[s * 2], r1 = x4[s * 2 + 1];
                    aX[0] += r0.x * w; aX[1] += r0.y * w; aX[2] += r0.z * w; aX[3] += r0.w * w;
                    aX[4] += r1.x * w; aX[5] += r1.y * w; aX[6] += r1.z * w; aX[7] += r1.w * w;
                }
            }
        }
        if (cnt > TSLOT - 1) {          // rare overflow (deg > 47)
            size_t gn = (size_t)g * Nn + n;
            float dn = dis[gn];
            int start = startA[gn];
            const float* dsg = dis + (size_t)g * Nn;
            for (int e = TSLOT - 1; e < cnt; ++e) {
                int s = csr[start + e];
                float w = dsg[s] * dn;
                float4 r0 = x4[s * 2], r1 = x4[s * 2 + 1];
                aX[0] += r0.x * w; aX[1] += r0.y * w; aX[2] += r0.z * w; aX[3] += r0.w * w;
                aX[4] += r1.x * w; aX[5] += r1.y * w; aX[6] += r1.z * w; aX[7] += r1.w * w;
            }
        }
    }
    // phase 1: h1 = relu(aX @ W1 + b1), W1/b1 uniform scalar loads, full unroll
    float h1r[64];
    {
        const float4* b14 = reinterpret_cast<const float4*>(b1);
#pragma unroll
        for (int f4 = 0; f4 < 16; ++f4) {
            float4 b = b14[f4];
            h1r[4 * f4 + 0] = b.x; h1r[4 * f4 + 1] = b.y;
            h1r[4 * f4 + 2] = b.z; h1r[4 * f4 + 3] = b.w;
        }
        const float4* W14 = reinterpret_cast<const float4*>(W1);
#pragma unroll
        for (int k = 0; k < 8; ++k) {
            float hk = aX[k];
#pragma unroll
            for (int f4 = 0; f4 < 16; ++f4) {
                float4 w = W14[k * 16 + f4];
                h1r[4 * f4 + 0] += hk * w.x; h1r[4 * f4 + 1] += hk * w.y;
                h1r[4 * f4 + 2] += hk * w.z; h1r[4 * f4 + 3] += hk * w.w;
            }
        }
#pragma unroll
        for (int f = 0; f < 64; ++f) h1r[f] = fmaxf(h1r[f], 0.f);
    }
    // phase 2: t2 = h1 @ W2 (fp8 out), two 32-feature halves (caps live VGPRs),
    // FULL unroll everywhere -> constant indices -> no scratch. hf is a LOOP
    // variable (block-uniform W2 addresses -> s_load path; R4 lesson).
    uint4 oh[2][2];
    {
        const float4* W24 = reinterpret_cast<const float4*>(W2);
#pragma unroll
        for (int hf = 0; hf < 2; ++hf) {
            float acch[32];
#pragma unroll
            for (int f = 0; f < 32; ++f) acch[f] = 0.f;
#pragma unroll
            for (int k = 0; k < 64; ++k) {
                float hk = h1r[k];
#pragma unroll
                for (int f4 = 0; f4 < 8; ++f4) {
                    float4 w = W24[k * 16 + hf * 8 + f4];
                    acch[4 * f4 + 0] += hk * w.x; acch[4 * f4 + 1] += hk * w.y;
                    acch[4 * f4 + 2] += hk * w.z; acch[4 * f4 + 3] += hk * w.w;
                }
            }
            oh[hf][0].x = fp8_pack4(acch[0],  acch[1],  acch[2],  acch[3]);
            oh[hf][0].y = fp8_pack4(acch[4],  acch[5],  acch[6],  acch[7]);
            oh[hf][0].z = fp8_pack4(acch[8],  acch[9],  acch[10], acch[11]);
            oh[hf][0].w = fp8_pack4(acch[12], acch[13], acch[14], acch[15]);
            oh[hf][1].x = fp8_pack4(acch[16], acch[17], acch[18], acch[19]);
            oh[hf][1].y = fp8_pack4(acch[20], acch[21], acch[22], acch[23]);
            oh[hf][1].z = fp8_pack4(acch[24], acch[25], acch[26], acch[27]);
            oh[hf][1].w = fp8_pack4(acch[28], acch[29], acch[30], acch[31]);
        }
    }
    if (valid) {
        uint4* op = reinterpret_cast<uint4*>(t2f + ((size_t)g * Nn + n) * 64);
        op[0] = oh[0][0]; op[1] = oh[0][1]; op[2] = oh[1][0]; op[3] = oh[1][1];
    }
}

// ---- K3: LDS-staged aggregation of t2 (fp8) + relu + mean-pool.
// 1-deep et prefetch (R9): issue et[e+1] before the ~112-inst edge body.
__global__ void __launch_bounds__(1024, 1)
k_aggF(const unsigned char* __restrict__ t2f, const unsigned* __restrict__ ellT,
       const int* __restrict__ cntS, const int* __restrict__ ordS,
       const int* __restrict__ startA, const int* __restrict__ csr,
       const float* __restrict__ dis, const float* __restrict__ bias,
       float* __restrict__ emb) {
    __shared__ uint4 stage[Nn * 5];     // 160,000 B; row s at stage[s*5 .. s*5+3]
    int i = blockIdx.x;                 // 240 = 8 xcd * 15 frames * 2 halves
    int xcd = i & 7;
    int j = i >> 3;                     // 0..29
    int g = xcd * 15 + (j >> 1);
    int half = j & 1;
    int tid = threadIdx.x;              // 0..1023
    int w = tid >> 6, lane = tid & 63;
    // stage entire frame t2 (fp8) into LDS with padded stride
    {
        const uint4* src = reinterpret_cast<const uint4*>(t2f + (size_t)g * Nn * 64);
        for (int it = tid; it < Nn * 4; it += 1024)
            stage[(it >> 2) * 5 + (it & 3)] = src[it];
    }
    __syncthreads();
#define ROWFMA(dw, base) { float o_[4]; fp8x4_dec(dw, o_); \
    acc[base + 0] += o_[0] * wt; acc[base + 1] += o_[1] * wt; \
    acc[base + 2] += o_[2] * wt; acc[base + 3] += o_[3] * wt; }
#define EDGEFMA(s, wt) { \
    uint4 r0 = stage[(s) * 5], r1 = stage[(s) * 5 + 1]; \
    uint4 r2 = stage[(s) * 5 + 2], r3 = stage[(s) * 5 + 3]; \
    ROWFMA(r0.x, 0)  ROWFMA(r0.y, 4)  ROWFMA(r0.z, 8)  ROWFMA(r0.w, 12) \
    ROWFMA(r1.x, 16) ROWFMA(r1.y, 20) ROWFMA(r1.z, 24) ROWFMA(r1.w, 28) \
    ROWFMA(r2.x, 32) ROWFMA(r2.y, 36) ROWFMA(r2.z, 40) ROWFMA(r2.w, 44) \
    ROWFMA(r3.x, 48) ROWFMA(r3.y, 52) ROWFMA(r3.z, 56) ROWFMA(r3.w, 60) }
    int po = w * 64 + lane;             // 0..1023
    int p = half * 1000 + po;           // sorted position
    bool valid = (po < 1000);
    size_t gp = (size_t)g * Nn + (valid ? p : 0);
    int cnt = valid ? cntS[gp] : 0;
    int myc = valid ? (min(cnt, TSLOT - 1) + 1) : 0;
    float acc[64];
#pragma unroll
    for (int k = 0; k < 64; ++k) acc[k] = 0.f;
    const unsigned* et = ellT + (size_t)g * TSLOT * Nn + (valid ? p : 0);
    unsigned u_cur = (0 < myc) ? et[0] : 0u;
    for (int e = 0; e < TSLOT; ++e) {
        if (!__any(e < myc)) break;
        unsigned u_nxt = ((e + 1) < TSLOT && (e + 1) < myc)
                             ? et[(size_t)(e + 1) * Nn] : 0u;   // issued early
        if (e < myc) {
            float wt = __uint_as_float(u_cur & 0xffff0000u);
            int s = u_cur & 0xffffu;
            EDGEFMA(s, wt)
        }
        u_cur = u_nxt;
    }
    if (cnt > TSLOT - 1) {              // rare overflow (deg > 47)
        int n = ordS[gp];
        size_t gn = (size_t)g * Nn + n;
        float dn = dis[gn];
        int start = startA[gn];
        const float* dsg = dis + (size_t)g * Nn;
        for (int e = TSLOT - 1; e < cnt; ++e) {
            int s = csr[start + e];
            float wt = dsg[s] * dn;
            EDGEFMA(s, wt)
        }
    }
#undef EDGEFMA
#undef ROWFMA
    // bias + relu + per-feature butterfly pool over the wave's 64 positions
    float pool = 0.f;
#pragma unroll
    for (int k = 0; k < 64; ++k) {
        float v = valid ? fmaxf(acc[k] + bias[k], 0.f) : 0.f;
        v += __shfl_xor(v, 1);  v += __shfl_xor(v, 2);  v += __shfl_xor(v, 4);
        v += __shfl_xor(v, 8);  v += __shfl_xor(v, 16); v += __shfl_xor(v, 32);
        if (lane == k) pool = v;
    }
    atomicAdd(&emb[g * 64 + lane], pool * (1.0f / Nn));
}

// ---- K5: sequential GRU over T with FUSED gi precompute (k_gi removed).
__global__ void __launch_bounds__(768, 1)
k_gru_seq(const float* __restrict__ emb, const float* __restrict__ W_ih,
          const float* __restrict__ b_ih, const float* __restrict__ W_hh,
          const float* __restrict__ b_hh, const float* __restrict__ fc_w,
          const float* __restrict__ fc_b, float* __restrict__ out) {
    __shared__ float h[Fg];
    __shared__ float part[768];
    __shared__ float embs[Tt][64];       // 7.7 KB
    __shared__ float pgi[Tt][768];       // 92 KB: gi half-dots
    int b = blockIdx.x;                  // batch
    int tid = threadIdx.x;               // 0..767
    int row = tid >> 1;                  // gate-row 0..383
    int half = tid & 1;                  // which 64-slice of k
    float w[64];
    const float* wr = W_hh + (size_t)row * Fg + half * 64;
#pragma unroll
    for (int i = 0; i < 64; ++i) w[i] = wr[i];
    float wih[32];
    const float* wir = W_ih + (size_t)row * 64 + half * 32;
#pragma unroll
    for (int i = 0; i < 32; ++i) wih[i] = wir[i];
    // stage emb rows for this batch
    for (int it = tid; it < Tt * 64; it += 768)
        embs[it >> 6][it & 63] = emb[((size_t)b * Tt) * 64 + it];
    if (tid < Fg) h[tid] = 0.f;
    __syncthreads();
    // precompute gi half-dots for all timesteps (independent per thread)
    for (int t = 0; t < Tt; ++t) {
        const float* e = &embs[t][half * 32];
        float a0 = 0.f, a1 = 0.f, a2 = 0.f, a3 = 0.f;
#pragma unroll
        for (int i = 0; i < 8; ++i) {
            a0 += wih[4 * i + 0] * e[4 * i + 0];
            a1 += wih[4 * i + 1] * e[4 * i + 1];
            a2 += wih[4 * i + 2] * e[4 * i + 2];
            a3 += wih[4 * i + 3] * e[4 * i + 3];
        }
        pgi[t][tid] = (a0 + a1) + (a2 + a3);
    }
    __syncthreads();
    for (int t = 0; t < Tt; ++t) {
        const float* hh = &h[half * 64];
        float a0 = 0.f, a1 = 0.f, a2 = 0.f, a3 = 0.f;
#pragma unroll
        for (int i = 0; i < 16; ++i) {
            a0 += w[4 * i + 0] * hh[4 * i + 0];
            a1 += w[4 * i + 1] * hh[4 * i + 1];
            a2 += w[4 * i + 2] * hh[4 * i + 2];
            a3 += w[4 * i + 3] * hh[4 * i + 3];
        }
        part[tid] = (a0 + a1) + (a2 + a3);
        __syncthreads();
        if (tid < Fg) {
            int j = tid;
            float hr = b_hh[j]       + part[2 * j]           + part[2 * j + 1];
            float hz = b_hh[128 + j] + part[2 * (128 + j)]   + part[2 * (128 + j) + 1];
            float hn = b_hh[256 + j] + part[2 * (256 + j)]   + part[2 * (256 + j) + 1];
            float gr = b_ih[j]       + pgi[t][2 * j]         + pgi[t][2 * j + 1];
            float gz = b_ih[128 + j] + pgi[t][2 * (128 + j)] + pgi[t][2 * (128 + j) + 1];
            float gn = b_ih[256 + j] + pgi[t][2 * (256 + j)] + pgi[t][2 * (256 + j) + 1];
            float r  = 1.f / (1.f + expf(-(gr + hr)));
            float z  = 1.f / (1.f + expf(-(gz + hz)));
            float nn = tanhf(gn + r * hn);
            h[j] = (1.f - z) * nn + z * h[j];
        }
        __syncthreads();
    }
    if (tid < 2) {
        float acc = fc_b[tid];
        for (int k = 0; k < Fg; ++k) acc += fc_w[tid * Fg + k] * h[k];
        out[b * 2 + tid] = acc;
    }
}

// ----------------------------------------------------------------- launcher
extern "C" void kernel_launch(void* const* d_in, const int* in_sizes, int n_in,
                              void* d_out, int out_size, void* d_ws, size_t ws_size,
                              hipStream_t stream) {
    const float* x     = (const float*)d_in[0];
    const int*   ei    = (const int*)  d_in[1];
    const float* W1    = (const float*)d_in[2];
    const float* b1    = (const float*)d_in[3];
    const float* W2    = (const float*)d_in[4];
    const float* b2    = (const float*)d_in[5];
    const float* W_ih  = (const float*)d_in[6];
    const float* W_hh  = (const float*)d_in[7];
    const float* b_ih  = (const float*)d_in[8];
    const float* b_hh  = (const float*)d_in[9];
    const float* fc_w  = (const float*)d_in[10];
    const float* fc_b  = (const float*)d_in[11];
    float* out = (float*)d_out;

    char* ws = (char*)d_ws;
    size_t off = 0;
    auto alloc = [&](size_t bytes) -> void* {
        void* p = ws + off;
        off = (off + bytes + 255) & ~(size_t)255;
        return p;
    };
    float*    dis    = (float*)   alloc((size_t)G * Nn * 4);
    int*      startA = (int*)     alloc((size_t)G * Nn * 4);
    int*      cntS   = (int*)     alloc((size_t)G * Nn * 4);
    int*      ordS   = (int*)     alloc((size_t)G * Nn * 4);
    int*      csr    = (int*)     alloc((size_t)G * 4 * QCAP * 4);
    unsigned* ellT   = (unsigned*)alloc((size_t)G * TSLOT * Nn * 4);
    unsigned char* t2f = (unsigned char*)alloc((size_t)G * Nn * 64);
    float*    emb    = (float*)   alloc((size_t)G * 64 * 4);
    (void)ws_size; (void)in_sizes; (void)n_in; (void)out_size;

    hipLaunchKernelGGL(k_build,   dim3(G), dim3(1024), 0, stream, ei, dis, startA, csr, ellT, cntS, ordS, emb);
    hipLaunchKernelGGL(k_fused,   dim3(960), dim3(256), 0, stream, x, ellT, cntS, ordS, startA, csr, dis, W1, b1, W2, t2f);
    hipLaunchKernelGGL(k_aggF,    dim3(240), dim3(1024), 0, stream, t2f, ellT, cntS, ordS, startA, csr, dis, b2, emb);
    hipLaunchKernelGGL(k_gru_seq, dim3(Bb), dim3(768), 0, stream, emb, W_ih, b_ih, W_hh, b_hh, fc_w, fc_b, out);
}

// Round 12
// 255.470 us; speedup vs baseline: 1.0469x; 1.0413x over previous
//
#include <hip/hip_runtime.h>
#include <math.h>

// Problem constants (fixed by the reference)
#define G    120     // B*T frames
#define Nn   2000    // nodes per frame
#define Ee   32000   // edges per frame
#define Tt   30
#define Bb   4
#define Fg   128     // GRU hidden
#define QCAP 9216    // global CSR spill capacity per (frame,quadrant-slot); 4*QCAP/frame
#define TSLOT 48     // transposed-ELL slots/node: slot0=self + up to 47 edges

static __device__ __forceinline__ unsigned short f2bf(float f) {
    unsigned u = __float_as_uint(f);
    u += 0x7fffu + ((u >> 16) & 1u);          // round-to-nearest-even
    return (unsigned short)(u >> 16);
}

// ---------------- fp8 e4m3 encode/decode: HW builtins if available, SW fallback.
#if defined(__has_builtin)
#if __has_builtin(__builtin_amdgcn_cvt_f32_fp8) && __has_builtin(__builtin_amdgcn_cvt_pk_fp8_f32)
#define HW_FP8 1
#endif
#if __has_builtin(__builtin_amdgcn_cvt_pk_f32_fp8)
#define HW_FP8_PK 1
typedef float floatx2 __attribute__((ext_vector_type(2)));
#endif
#endif

static __device__ __forceinline__ unsigned fp8_enc_sw(float x) {
    unsigned s = (__float_as_uint(x) >> 24) & 0x80u;
    float ax = fminf(fabsf(x), 448.f);
    unsigned em;
    if (ax < 0.015625f) {
        em = (unsigned)__float2int_rn(ax * 512.f);
    } else {
        int e = (int)(__float_as_uint(ax) >> 23) - 127;
        float r = ax * __uint_as_float((unsigned)((130 - e) << 23));
        int q = __float2int_rn(r);
        em = (unsigned)(((e + 7) << 3) + (q - 8));
        em = min(em, 126u);
    }
    return s | em;
}
static __device__ __forceinline__ float fp8_dec_sw(unsigned b) {
    unsigned em = b & 0x7fu;
    float mag;
    if (em < 8u) mag = (float)em * 0.001953125f;
    else mag = __uint_as_float((((em >> 3) + 120u) << 23) | ((em & 7u) << 20));
    return (b & 0x80u) ? -mag : mag;
}
static __device__ __forceinline__ unsigned fp8_pack4(float a, float b, float c, float d) {
#ifdef HW_FP8
    int w = __builtin_amdgcn_cvt_pk_fp8_f32(a, b, 0, false);
    w = __builtin_amdgcn_cvt_pk_fp8_f32(c, d, w, true);
    return (unsigned)w;
#else
    return fp8_enc_sw(a) | (fp8_enc_sw(b) << 8) | (fp8_enc_sw(c) << 16) | (fp8_enc_sw(d) << 24);
#endif
}
static __device__ __forceinline__ void fp8x4_dec(unsigned dw, float* o) {
#ifdef HW_FP8_PK
    floatx2 lo = __builtin_amdgcn_cvt_pk_f32_fp8((int)dw, false);
    floatx2 hi = __builtin_amdgcn_cvt_pk_f32_fp8((int)dw, true);
    o[0] = lo[0]; o[1] = lo[1]; o[2] = hi[0]; o[3] = hi[1];
#else
    o[0] = fp8_dec_sw(dw & 0xffu);
    o[1] = fp8_dec_sw((dw >> 8) & 0xffu);
    o[2] = fp8_dec_sw((dw >> 16) & 0xffu);
    o[3] = fp8_dec_sw((dw >> 24) & 0xffu);
#endif
}

// ---- K1 (R12): MERGED whole-frame build + fused GCN layer-1+2.
// 2 blocks per frame (grid 240 -> ~full chip). Each block runs the full build
// for its frame (duplicated across the half-pair: LDS-bound, same wall time on
// 2x CUs), emits its HALF of the sorted columns (ellT/cntS/ordS/startA), then
// computes layer-1+2 for its half's 1000 nodes with gather indices from LDS
// csr_l (removes k_fused's standalone 62-86 µs whose et reads paid L2 latency).
// LDS = 128K(csr)+4x8K+bins = 160.5KB (fits, 1 block/CU).
__global__ void __launch_bounds__(1024, 1)
k_bfuse(const int* __restrict__ ei, const float* __restrict__ x,
        const float* __restrict__ W1, const float* __restrict__ b1,
        const float* __restrict__ W2,
        float* __restrict__ dis, int* __restrict__ startA, int* __restrict__ csr,
        unsigned* __restrict__ ellT, int* __restrict__ cntS, int* __restrict__ ordS,
        float* __restrict__ emb, unsigned char* __restrict__ t2f) {
    __shared__ int   csr_l[Ee];       // 128,000 B — whole-frame CSR
    __shared__ int   hist[Nn];        // counts -> inclusive scan -> cursor
    __shared__ int   cntL[Nn];
    __shared__ int   nodeAt[Nn];      // sorted position -> node
    __shared__ float disl[Nn];
    __shared__ int   dh[64];          // degree histogram, then cursor
    __shared__ int   db[64];          // degree-bin exclusive base
    __shared__ int   ovfS;
    int i = blockIdx.x;               // 0..239
    int g = i >> 1;                   // frame
    int half = i & 1;                 // which 1000 sorted columns this block owns
    int tid = threadIdx.x;
    // P1: init
    for (int idx = tid; idx < Nn; idx += 1024) hist[idx] = 0;
    if (tid < 64) dh[tid] = 0;
    if (tid == 0) ovfS = 0;
    if (tid < 64) emb[g * 64 + tid] = 0.f;     // both halves write 0 (benign)
    __syncthreads();
    // P2: full-frame histogram of destinations
    const int* srcp = ei + (size_t)g * 2 * Ee;
    const int* dstp = srcp + Ee;
    for (int it = tid; it < Ee / 4; it += 1024) {
        int4 d = reinterpret_cast<const int4*>(dstp)[it];
        atomicAdd(&hist[d.x], 1);
        atomicAdd(&hist[d.y], 1);
        atomicAdd(&hist[d.z], 1);
        atomicAdd(&hist[d.w], 1);
    }
    __syncthreads();
    // P3a: cnt snapshot, dis (LDS + global), degree bins, overflow flag
    for (int idx = tid; idx < Nn; idx += 1024) {
        int c = hist[idx];
        cntL[idx] = c;
        float dv = rsqrtf((float)c + 1.0f);
        disl[idx] = dv;
        dis[(size_t)g * Nn + idx] = dv;        // identical write from both halves
        atomicAdd(&dh[min(c, 63)], 1);
        if (c > TSLOT - 1) atomicMax(&ovfS, 1);
    }
    __syncthreads();
    // P3b: in-place inclusive Hillis-Steele scan of hist over Nn=2000
    for (int off = 1; off < Nn; off <<= 1) {
        int i1 = tid + 1024;
        int v0 = (tid >= off) ? hist[tid - off] : 0;
        int v1 = (i1 < Nn && i1 >= off) ? hist[i1 - off] : 0;
        __syncthreads();
        hist[tid] += v0;
        if (i1 < Nn) hist[i1] += v1;
        __syncthreads();
    }
    // P3c: degree-bin exclusive scan (serial, 64 elems), then cursor=base
    if (tid == 0) {
        int s = 0;
        for (int b = 0; b < 64; ++b) { db[b] = s; s += dh[b]; }
    }
    __syncthreads();
    if (tid < 64) dh[tid] = db[tid];
    __syncthreads();
    // P3d: sorted-position assignment; convert hist from inclusive to cursor(=ex)
    for (int idx = tid; idx < Nn; idx += 1024) {
        int p = atomicAdd(&dh[min(cntL[idx], 63)], 1);
        nodeAt[p] = idx;
        hist[idx] -= cntL[idx];       // cursor = exclusive prefix
    }
    __syncthreads();
    // P4: fill whole-frame CSR (cursor partitions [0,Ee) exactly; no OOB)
    for (int it = tid; it < Ee / 4; it += 1024) {
        int4 d = reinterpret_cast<const int4*>(dstp)[it];
        int4 s = reinterpret_cast<const int4*>(srcp)[it];
        csr_l[atomicAdd(&hist[d.x], 1)] = s.x;
        csr_l[atomicAdd(&hist[d.y], 1)] = s.y;
        csr_l[atomicAdd(&hist[d.z], 1)] = s.z;
        csr_l[atomicAdd(&hist[d.w], 1)] = s.w;
    }
    __syncthreads();
    // P5: emit OWN-HALF sorted columns. After P4, hist[n] = ex(n)+cnt(n).
    if (tid < 1000) {
        int c = half * 1000 + tid;
        int n2 = nodeAt[c];
        int cnt2 = cntL[n2];
        int ex2 = hist[n2] - cnt2;
        size_t gc = (size_t)g * Nn + c;
        cntS[gc] = cnt2;
        ordS[gc] = n2;
        startA[(size_t)g * Nn + n2] = g * 4 * QCAP + ex2;
        float dn2 = disl[n2];
        unsigned* et = ellT + (size_t)g * TSLOT * Nn + c;
        et[0] = (unsigned)n2 | ((unsigned)f2bf(dn2 * dn2) << 16);
        int m2 = min(cnt2, TSLOT - 1);
        for (int e = 0; e < m2; ++e) {
            int s = csr_l[ex2 + e];
            et[(size_t)(e + 1) * Nn] = (unsigned)s | ((unsigned)f2bf(disl[s] * dn2) << 16);
        }
    }
    // P6: global CSR spill only if some node overflowed (half 0 writes it)
    if (ovfS && half == 0) {
        int* cg = csr + (size_t)g * 4 * QCAP;
        for (int it = tid; it < Ee; it += 1024) cg[it] = csr_l[it];
    }
    __syncthreads();
    // P7: fused GCN layer-1+2 for this half's 1000 sorted positions.
    // Gather indices/weights from LDS (csr_l/disl); only x rows hit L2.
    // Same FP accumulation order as the old k_fused (self then CSR order).
    if (tid < 1000) {
        int c = half * 1000 + tid;
        int n = nodeAt[c];
        int cntn = cntL[n];
        int ex = hist[n] - cntn;
        float dn = disl[n];
        const float4* x4 = reinterpret_cast<const float4*>(x + (size_t)g * Nn * 8);
        // phase 0: aggregate x (self-loop first, then edges; 8-wide batches)
        float aX[8];
        {
            float w = dn * dn;
            float4 r0 = x4[n * 2], r1 = x4[n * 2 + 1];
            aX[0] = r0.x * w; aX[1] = r0.y * w; aX[2] = r0.z * w; aX[3] = r0.w * w;
            aX[4] = r1.x * w; aX[5] = r1.y * w; aX[6] = r1.z * w; aX[7] = r1.w * w;
        }
        for (int e0 = 0; e0 < cntn; e0 += 8) {
            int sb[8];
#pragma unroll
            for (int k2 = 0; k2 < 8; ++k2)
                sb[k2] = (e0 + k2 < cntn) ? csr_l[ex + e0 + k2] : -1;
#pragma unroll
            for (int k2 = 0; k2 < 8; ++k2) {
                if (sb[k2] >= 0) {
                    int s = sb[k2];
                    float w = disl[s] * dn;
                    float4 r0 = x4[s * 2], r1 = x4[s * 2 + 1];
                    aX[0] += r0.x * w; aX[1] += r0.y * w; aX[2] += r0.z * w; aX[3] += r0.w * w;
                    aX[4] += r1.x * w; aX[5] += r1.y * w; aX[6] += r1.z * w; aX[7] += r1.w * w;
                }
            }
        }
        // phase 1: h1 = relu(aX @ W1 + b1) — block-uniform weight loads
        float h1r[64];
        {
            const float4* b14 = reinterpret_cast<const float4*>(b1);
#pragma unroll
            for (int f4 = 0; f4 < 16; ++f4) {
                float4 b = b14[f4];
                h1r[4 * f4 + 0] = b.x; h1r[4 * f4 + 1] = b.y;
                h1r[4 * f4 + 2] = b.z; h1r[4 * f4 + 3] = b.w;
            }
            const float4* W14 = reinterpret_cast<const float4*>(W1);
#pragma unroll
            for (int k2 = 0; k2 < 8; ++k2) {
                float hk = aX[k2];
#pragma unroll
                for (int f4 = 0; f4 < 16; ++f4) {
                    float4 w = W14[k2 * 16 + f4];
                    h1r[4 * f4 + 0] += hk * w.x; h1r[4 * f4 + 1] += hk * w.y;
                    h1r[4 * f4 + 2] += hk * w.z; h1r[4 * f4 + 3] += hk * w.w;
                }
            }
#pragma unroll
            for (int f = 0; f < 64; ++f) h1r[f] = fmaxf(h1r[f], 0.f);
        }
        // phase 2: t2 = h1 @ W2 (fp8 out), two 32-feature halves; hf is a LOOP
        // variable (block-uniform W2 addresses -> s_load path; R4 lesson)
        uint4 oh[2][2];
        {
            const float4* W24 = reinterpret_cast<const float4*>(W2);
#pragma unroll
            for (int hf = 0; hf < 2; ++hf) {
                float acch[32];
#pragma unroll
                for (int f = 0; f < 32; ++f) acch[f] = 0.f;
#pragma unroll
                for (int k2 = 0; k2 < 64; ++k2) {
                    float hk = h1r[k2];
#pragma unroll
                    for (int f4 = 0; f4 < 8; ++f4) {
                        float4 w = W24[k2 * 16 + hf * 8 + f4];
                        acch[4 * f4 + 0] += hk * w.x; acch[4 * f4 + 1] += hk * w.y;
                        acch[4 * f4 + 2] += hk * w.z; acch[4 * f4 + 3] += hk * w.w;
                    }
                }
                oh[hf][0].x = fp8_pack4(acch[0],  acch[1],  acch[2],  acch[3]);
                oh[hf][0].y = fp8_pack4(acch[4],  acch[5],  acch[6],  acch[7]);
                oh[hf][0].z = fp8_pack4(acch[8],  acch[9],  acch[10], acch[11]);
                oh[hf][0].w = fp8_pack4(acch[12], acch[13], acch[14], acch[15]);
                oh[hf][1].x = fp8_pack4(acch[16], acch[17], acch[18], acch[19]);
                oh[hf][1].y = fp8_pack4(acch[20], acch[21], acch[22], acch[23]);
                oh[hf][1].z = fp8_pack4(acch[24], acch[25], acch[26], acch[27]);
                oh[hf][1].w = fp8_pack4(acch[28], acch[29], acch[30], acch[31]);
            }
        }
        uint4* op = reinterpret_cast<uint4*>(t2f + ((size_t)g * Nn + n) * 64);
        op[0] = oh[0][0]; op[1] = oh[0][1]; op[2] = oh[1][0]; op[3] = oh[1][1];
    }
}

// ---- K3: LDS-staged aggregation of t2 (fp8) + relu + mean-pool.
// 1-deep et prefetch (R9): issue et[e+1] before the ~112-inst edge body.
__global__ void __launch_bounds__(1024, 1)
k_aggF(const unsigned char* __restrict__ t2f, const unsigned* __restrict__ ellT,
       const int* __restrict__ cntS, const int* __restrict__ ordS,
       const int* __restrict__ startA, const int* __restrict__ csr,
       const float* __restrict__ dis, const float* __restrict__ bias,
       float* __restrict__ emb) {
    __shared__ uint4 stage[Nn * 5];     // 160,000 B; row s at stage[s*5 .. s*5+3]
    int i = blockIdx.x;                 // 240 = 8 xcd * 15 frames * 2 halves
    int xcd = i & 7;
    int j = i >> 3;                     // 0..29
    int g = xcd * 15 + (j >> 1);
    int half = j & 1;
    int tid = threadIdx.x;              // 0..1023
    int w = tid >> 6, lane = tid & 63;
    // stage entire frame t2 (fp8) into LDS with padded stride
    {
        const uint4* src = reinterpret_cast<const uint4*>(t2f + (size_t)g * Nn * 64);
        for (int it = tid; it < Nn * 4; it += 1024)
            stage[(it >> 2) * 5 + (it & 3)] = src[it];
    }
    __syncthreads();
#define ROWFMA(dw, base) { float o_[4]; fp8x4_dec(dw, o_); \
    acc[base + 0] += o_[0] * wt; acc[base + 1] += o_[1] * wt; \
    acc[base + 2] += o_[2] * wt; acc[base + 3] += o_[3] * wt; }
#define EDGEFMA(s, wt) { \
    uint4 r0 = stage[(s) * 5], r1 = stage[(s) * 5 + 1]; \
    uint4 r2 = stage[(s) * 5 + 2], r3 = stage[(s) * 5 + 3]; \
    ROWFMA(r0.x, 0)  ROWFMA(r0.y, 4)  ROWFMA(r0.z, 8)  ROWFMA(r0.w, 12) \
    ROWFMA(r1.x, 16) ROWFMA(r1.y, 20) ROWFMA(r1.z, 24) ROWFMA(r1.w, 28) \
    ROWFMA(r2.x, 32) ROWFMA(r2.y, 36) ROWFMA(r2.z, 40) ROWFMA(r2.w, 44) \
    ROWFMA(r3.x, 48) ROWFMA(r3.y, 52) ROWFMA(r3.z, 56) ROWFMA(r3.w, 60) }
    int po = w * 64 + lane;             // 0..1023
    int p = half * 1000 + po;           // sorted position
    bool valid = (po < 1000);
    size_t gp = (size_t)g * Nn + (valid ? p : 0);
    int cnt = valid ? cntS[gp] : 0;
    int myc = valid ? (min(cnt, TSLOT - 1) + 1) : 0;
    float acc[64];
#pragma unroll
    for (int k = 0; k < 64; ++k) acc[k] = 0.f;
    const unsigned* et = ellT + (size_t)g * TSLOT * Nn + (valid ? p : 0);
    unsigned u_cur = (0 < myc) ? et[0] : 0u;
    for (int e = 0; e < TSLOT; ++e) {
        if (!__any(e < myc)) break;
        unsigned u_nxt = ((e + 1) < TSLOT && (e + 1) < myc)
                             ? et[(size_t)(e + 1) * Nn] : 0u;   // issued early
        if (e < myc) {
            float wt = __uint_as_float(u_cur & 0xffff0000u);
            int s = u_cur & 0xffffu;
            EDGEFMA(s, wt)
        }
        u_cur = u_nxt;
    }
    if (cnt > TSLOT - 1) {              // rare overflow (deg > 47)
        int n = ordS[gp];
        size_t gn = (size_t)g * Nn + n;
        float dn = dis[gn];
        int start = startA[gn];
        const float* dsg = dis + (size_t)g * Nn;
        for (int e = TSLOT - 1; e < cnt; ++e) {
            int s = csr[start + e];
            float wt = dsg[s] * dn;
            EDGEFMA(s, wt)
        }
    }
#undef EDGEFMA
#undef ROWFMA
    // bias + relu + per-feature butterfly pool over the wave's 64 positions
    float pool = 0.f;
#pragma unroll
    for (int k = 0; k < 64; ++k) {
        float v = valid ? fmaxf(acc[k] + bias[k], 0.f) : 0.f;
        v += __shfl_xor(v, 1);  v += __shfl_xor(v, 2);  v += __shfl_xor(v, 4);
        v += __shfl_xor(v, 8);  v += __shfl_xor(v, 16); v += __shfl_xor(v, 32);
        if (lane == k) pool = v;
    }
    atomicAdd(&emb[g * 64 + lane], pool * (1.0f / Nn));
}

// ---- K5: sequential GRU over T with FUSED gi precompute (k_gi removed).
__global__ void __launch_bounds__(768, 1)
k_gru_seq(const float* __restrict__ emb, const float* __restrict__ W_ih,
          const float* __restrict__ b_ih, const float* __restrict__ W_hh,
          const float* __restrict__ b_hh, const float* __restrict__ fc_w,
          const float* __restrict__ fc_b, float* __restrict__ out) {
    __shared__ float h[Fg];
    __shared__ float part[768];
    __shared__ float embs[Tt][64];       // 7.7 KB
    __shared__ float pgi[Tt][768];       // 92 KB: gi half-dots
    int b = blockIdx.x;                  // batch
    int tid = threadIdx.x;               // 0..767
    int row = tid >> 1;                  // gate-row 0..383
    int half = tid & 1;                  // which 64-slice of k
    float w[64];
    const float* wr = W_hh + (size_t)row * Fg + half * 64;
#pragma unroll
    for (int i = 0; i < 64; ++i) w[i] = wr[i];
    float wih[32];
    const float* wir = W_ih + (size_t)row * 64 + half * 32;
#pragma unroll
    for (int i = 0; i < 32; ++i) wih[i] = wir[i];
    // stage emb rows for this batch
    for (int it = tid; it < Tt * 64; it += 768)
        embs[it >> 6][it & 63] = emb[((size_t)b * Tt) * 64 + it];
    if (tid < Fg) h[tid] = 0.f;
    __syncthreads();
    // precompute gi half-dots for all timesteps (independent per thread)
    for (int t = 0; t < Tt; ++t) {
        const float* e = &embs[t][half * 32];
        float a0 = 0.f, a1 = 0.f, a2 = 0.f, a3 = 0.f;
#pragma unroll
        for (int i = 0; i < 8; ++i) {
            a0 += wih[4 * i + 0] * e[4 * i + 0];
            a1 += wih[4 * i + 1] * e[4 * i + 1];
            a2 += wih[4 * i + 2] * e[4 * i + 2];
            a3 += wih[4 * i + 3] * e[4 * i + 3];
        }
        pgi[t][tid] = (a0 + a1) + (a2 + a3);
    }
    __syncthreads();
    for (int t = 0; t < Tt; ++t) {
        const float* hh = &h[half * 64];
        float a0 = 0.f, a1 = 0.f, a2 = 0.f, a3 = 0.f;
#pragma unroll
        for (int i = 0; i < 16; ++i) {
            a0 += w[4 * i + 0] * hh[4 * i + 0];
            a1 += w[4 * i + 1] * hh[4 * i + 1];
            a2 += w[4 * i + 2] * hh[4 * i + 2];
            a3 += w[4 * i + 3] * hh[4 * i + 3];
        }
        part[tid] = (a0 + a1) + (a2 + a3);
        __syncthreads();
        if (tid < Fg) {
            int j = tid;
            float hr = b_hh[j]       + part[2 * j]           + part[2 * j + 1];
            float hz = b_hh[128 + j] + part[2 * (128 + j)]   + part[2 * (128 + j) + 1];
            float hn = b_hh[256 + j] + part[2 * (256 + j)]   + part[2 * (256 + j) + 1];
            float gr = b_ih[j]       + pgi[t][2 * j]         + pgi[t][2 * j + 1];
            float gz = b_ih[128 + j] + pgi[t][2 * (128 + j)] + pgi[t][2 * (128 + j) + 1];
            float gn = b_ih[256 + j] + pgi[t][2 * (256 + j)] + pgi[t][2 * (256 + j) + 1];
            float r  = 1.f / (1.f + expf(-(gr + hr)));
            float z  = 1.f / (1.f + expf(-(gz + hz)));
            float nn = tanhf(gn + r * hn);
            h[j] = (1.f - z) * nn + z * h[j];
        }
        __syncthreads();
    }
    if (tid < 2) {
        float acc = fc_b[tid];
        for (int k = 0; k < Fg; ++k) acc += fc_w[tid * Fg + k] * h[k];
        out[b * 2 + tid] = acc;
    }
}

// ----------------------------------------------------------------- launcher
extern "C" void kernel_launch(void* const* d_in, const int* in_sizes, int n_in,
                              void* d_out, int out_size, void* d_ws, size_t ws_size,
                              hipStream_t stream) {
    const float* x     = (const float*)d_in[0];
    const int*   ei    = (const int*)  d_in[1];
    const float* W1    = (const float*)d_in[2];
    const float* b1    = (const float*)d_in[3];
    const float* W2    = (const float*)d_in[4];
    const float* b2    = (const float*)d_in[5];
    const float* W_ih  = (const float*)d_in[6];
    const float* W_hh  = (const float*)d_in[7];
    const float* b_ih  = (const float*)d_in[8];
    const float* b_hh  = (const float*)d_in[9];
    const float* fc_w  = (const float*)d_in[10];
    const float* fc_b  = (const float*)d_in[11];
    float* out = (float*)d_out;

    char* ws = (char*)d_ws;
    size_t off = 0;
    auto alloc = [&](size_t bytes) -> void* {
        void* p = ws + off;
        off = (off + bytes + 255) & ~(size_t)255;
        return p;
    };
    float*    dis    = (float*)   alloc((size_t)G * Nn * 4);
    int*      startA = (int*)     alloc((size_t)G * Nn * 4);
    int*      cntS   = (int*)     alloc((size_t)G * Nn * 4);
    int*      ordS   = (int*)     alloc((size_t)G * Nn * 4);
    int*      csr    = (int*)     alloc((size_t)G * 4 * QCAP * 4);
    unsigned* ellT   = (unsigned*)alloc((size_t)G * TSLOT * Nn * 4);
    unsigned char* t2f = (unsigned char*)alloc((size_t)G * Nn * 64);
    float*    emb    = (float*)   alloc((size_t)G * 64 * 4);
    (void)ws_size; (void)in_sizes; (void)n_in; (void)out_size;

    hipLaunchKernelGGL(k_bfuse,   dim3(2 * G), dim3(1024), 0, stream,
                       ei, x, W1, b1, W2, dis, startA, csr, ellT, cntS, ordS, emb, t2f);
    hipLaunchKernelGGL(k_aggF,    dim3(240), dim3(1024), 0, stream, t2f, ellT, cntS, ordS, startA, csr, dis, b2, emb);
    hipLaunchKernelGGL(k_gru_seq, dim3(Bb), dim3(768), 0, stream, emb, W_ih, b_ih, W_hh, b_hh, fc_w, fc_b, out);
}

// Round 13
// 251.387 us; speedup vs baseline: 1.0639x; 1.0162x over previous
//
#include <hip/hip_runtime.h>
#include <math.h>

// Problem constants (fixed by the reference)
#define G    120     // B*T frames
#define Nn   2000    // nodes per frame
#define Ee   32000   // edges per frame
#define Tt   30
#define Bb   4
#define Fg   128     // GRU hidden
#define QCAP 9216    // global CSR spill capacity per (frame,quadrant-slot); 4*QCAP/frame
#define TSLOT 48     // transposed-ELL slots/node: slot0=self + up to 47 edges

static __device__ __forceinline__ unsigned short f2bf(float f) {
    unsigned u = __float_as_uint(f);
    u += 0x7fffu + ((u >> 16) & 1u);          // round-to-nearest-even
    return (unsigned short)(u >> 16);
}

// ---------------- fp8 e4m3 encode/decode: HW builtins if available, SW fallback.
#if defined(__has_builtin)
#if __has_builtin(__builtin_amdgcn_cvt_f32_fp8) && __has_builtin(__builtin_amdgcn_cvt_pk_fp8_f32)
#define HW_FP8 1
#endif
#if __has_builtin(__builtin_amdgcn_cvt_pk_f32_fp8)
#define HW_FP8_PK 1
typedef float floatx2 __attribute__((ext_vector_type(2)));
#endif
#endif

static __device__ __forceinline__ unsigned fp8_enc_sw(float x) {
    unsigned s = (__float_as_uint(x) >> 24) & 0x80u;
    float ax = fminf(fabsf(x), 448.f);
    unsigned em;
    if (ax < 0.015625f) {
        em = (unsigned)__float2int_rn(ax * 512.f);
    } else {
        int e = (int)(__float_as_uint(ax) >> 23) - 127;
        float r = ax * __uint_as_float((unsigned)((130 - e) << 23));
        int q = __float2int_rn(r);
        em = (unsigned)(((e + 7) << 3) + (q - 8));
        em = min(em, 126u);
    }
    return s | em;
}
static __device__ __forceinline__ float fp8_dec_sw(unsigned b) {
    unsigned em = b & 0x7fu;
    float mag;
    if (em < 8u) mag = (float)em * 0.001953125f;
    else mag = __uint_as_float((((em >> 3) + 120u) << 23) | ((em & 7u) << 20));
    return (b & 0x80u) ? -mag : mag;
}
static __device__ __forceinline__ unsigned fp8_pack4(float a, float b, float c, float d) {
#ifdef HW_FP8
    int w = __builtin_amdgcn_cvt_pk_fp8_f32(a, b, 0, false);
    w = __builtin_amdgcn_cvt_pk_fp8_f32(c, d, w, true);
    return (unsigned)w;
#else
    return fp8_enc_sw(a) | (fp8_enc_sw(b) << 8) | (fp8_enc_sw(c) << 16) | (fp8_enc_sw(d) << 24);
#endif
}
static __device__ __forceinline__ void fp8x4_dec(unsigned dw, float* o) {
#ifdef HW_FP8_PK
    floatx2 lo = __builtin_amdgcn_cvt_pk_f32_fp8((int)dw, false);
    floatx2 hi = __builtin_amdgcn_cvt_pk_f32_fp8((int)dw, true);
    o[0] = lo[0]; o[1] = lo[1]; o[2] = hi[0]; o[3] = hi[1];
#else
    o[0] = fp8_dec_sw(dw & 0xffu);
    o[1] = fp8_dec_sw((dw >> 8) & 0xffu);
    o[2] = fp8_dec_sw((dw >> 16) & 0xffu);
    o[3] = fp8_dec_sw((dw >> 24) & 0xffu);
#endif
}

// ---- K1 (R13): merged build + fused GCN layer-1+2, with XCD-CO-LOCATED
// half-pairs: decode xcd=i&7, half=j&1 so the two blocks of a frame differ by
// 8 in blockIdx -> same XCD under round-robin -> the pair SHARES its frame's
// edge-list and x reads in that XCD's L2 (R12 decode put them on different
// XCDs: FETCH 50MB for a 31MB edge input). Same scheme k_aggF already uses.
// LDS = 128K(csr)+4x8K+bins = 160.5KB (fits, 1 block/CU).
__global__ void __launch_bounds__(1024, 1)
k_bfuse(const int* __restrict__ ei, const float* __restrict__ x,
        const float* __restrict__ W1, const float* __restrict__ b1,
        const float* __restrict__ W2,
        float* __restrict__ dis, int* __restrict__ startA, int* __restrict__ csr,
        unsigned* __restrict__ ellT, int* __restrict__ cntS, int* __restrict__ ordS,
        float* __restrict__ emb, unsigned char* __restrict__ t2f) {
    __shared__ int   csr_l[Ee];       // 128,000 B — whole-frame CSR
    __shared__ int   hist[Nn];        // counts -> inclusive scan -> cursor
    __shared__ int   cntL[Nn];
    __shared__ int   nodeAt[Nn];      // sorted position -> node
    __shared__ float disl[Nn];
    __shared__ int   dh[64];          // degree histogram, then cursor
    __shared__ int   db[64];          // degree-bin exclusive base
    __shared__ int   ovfS;
    int i = blockIdx.x;               // 0..239
    int xcd = i & 7;
    int j = i >> 3;                   // 0..29
    int g = xcd * 15 + (j >> 1);      // frame (pair co-located on one XCD)
    int half = j & 1;                 // which 1000 sorted columns this block owns
    int tid = threadIdx.x;
    // P1: init
    for (int idx = tid; idx < Nn; idx += 1024) hist[idx] = 0;
    if (tid < 64) dh[tid] = 0;
    if (tid == 0) ovfS = 0;
    if (tid < 64) emb[g * 64 + tid] = 0.f;     // both halves write 0 (benign)
    __syncthreads();
    // P2: full-frame histogram of destinations
    const int* srcp = ei + (size_t)g * 2 * Ee;
    const int* dstp = srcp + Ee;
    for (int it = tid; it < Ee / 4; it += 1024) {
        int4 d = reinterpret_cast<const int4*>(dstp)[it];
        atomicAdd(&hist[d.x], 1);
        atomicAdd(&hist[d.y], 1);
        atomicAdd(&hist[d.z], 1);
        atomicAdd(&hist[d.w], 1);
    }
    __syncthreads();
    // P3a: cnt snapshot, dis (LDS + global), degree bins, overflow flag
    for (int idx = tid; idx < Nn; idx += 1024) {
        int c = hist[idx];
        cntL[idx] = c;
        float dv = rsqrtf((float)c + 1.0f);
        disl[idx] = dv;
        dis[(size_t)g * Nn + idx] = dv;        // identical write from both halves
        atomicAdd(&dh[min(c, 63)], 1);
        if (c > TSLOT - 1) atomicMax(&ovfS, 1);
    }
    __syncthreads();
    // P3b: in-place inclusive Hillis-Steele scan of hist over Nn=2000
    for (int off = 1; off < Nn; off <<= 1) {
        int i1 = tid + 1024;
        int v0 = (tid >= off) ? hist[tid - off] : 0;
        int v1 = (i1 < Nn && i1 >= off) ? hist[i1 - off] : 0;
        __syncthreads();
        hist[tid] += v0;
        if (i1 < Nn) hist[i1] += v1;
        __syncthreads();
    }
    // P3c: degree-bin exclusive scan (serial, 64 elems), then cursor=base
    if (tid == 0) {
        int s = 0;
        for (int b = 0; b < 64; ++b) { db[b] = s; s += dh[b]; }
    }
    __syncthreads();
    if (tid < 64) dh[tid] = db[tid];
    __syncthreads();
    // P3d: sorted-position assignment; convert hist from inclusive to cursor(=ex)
    for (int idx = tid; idx < Nn; idx += 1024) {
        int p = atomicAdd(&dh[min(cntL[idx], 63)], 1);
        nodeAt[p] = idx;
        hist[idx] -= cntL[idx];       // cursor = exclusive prefix
    }
    __syncthreads();
    // P4: fill whole-frame CSR (cursor partitions [0,Ee) exactly; no OOB)
    for (int it = tid; it < Ee / 4; it += 1024) {
        int4 d = reinterpret_cast<const int4*>(dstp)[it];
        int4 s = reinterpret_cast<const int4*>(srcp)[it];
        csr_l[atomicAdd(&hist[d.x], 1)] = s.x;
        csr_l[atomicAdd(&hist[d.y], 1)] = s.y;
        csr_l[atomicAdd(&hist[d.z], 1)] = s.z;
        csr_l[atomicAdd(&hist[d.w], 1)] = s.w;
    }
    __syncthreads();
    // P5: emit OWN-HALF sorted columns. After P4, hist[n] = ex(n)+cnt(n).
    if (tid < 1000) {
        int c = half * 1000 + tid;
        int n2 = nodeAt[c];
        int cnt2 = cntL[n2];
        int ex2 = hist[n2] - cnt2;
        size_t gc = (size_t)g * Nn + c;
        cntS[gc] = cnt2;
        ordS[gc] = n2;
        startA[(size_t)g * Nn + n2] = g * 4 * QCAP + ex2;
        float dn2 = disl[n2];
        unsigned* et = ellT + (size_t)g * TSLOT * Nn + c;
        et[0] = (unsigned)n2 | ((unsigned)f2bf(dn2 * dn2) << 16);
        int m2 = min(cnt2, TSLOT - 1);
        for (int e = 0; e < m2; ++e) {
            int s = csr_l[ex2 + e];
            et[(size_t)(e + 1) * Nn] = (unsigned)s | ((unsigned)f2bf(disl[s] * dn2) << 16);
        }
    }
    // P6: global CSR spill only if some node overflowed (half 0 writes it)
    if (ovfS && half == 0) {
        int* cg = csr + (size_t)g * 4 * QCAP;
        for (int it = tid; it < Ee; it += 1024) cg[it] = csr_l[it];
    }
    __syncthreads();
    // P7: fused GCN layer-1+2 for this half's 1000 sorted positions.
    // Gather indices/weights from LDS (csr_l/disl); only x rows hit L2.
    // Same FP accumulation order as the old k_fused (self then CSR order).
    if (tid < 1000) {
        int c = half * 1000 + tid;
        int n = nodeAt[c];
        int cntn = cntL[n];
        int ex = hist[n] - cntn;
        float dn = disl[n];
        const float4* x4 = reinterpret_cast<const float4*>(x + (size_t)g * Nn * 8);
        // phase 0: aggregate x (self-loop first, then edges; 8-wide batches)
        float aX[8];
        {
            float w = dn * dn;
            float4 r0 = x4[n * 2], r1 = x4[n * 2 + 1];
            aX[0] = r0.x * w; aX[1] = r0.y * w; aX[2] = r0.z * w; aX[3] = r0.w * w;
            aX[4] = r1.x * w; aX[5] = r1.y * w; aX[6] = r1.z * w; aX[7] = r1.w * w;
        }
        for (int e0 = 0; e0 < cntn; e0 += 8) {
            int sb[8];
#pragma unroll
            for (int k2 = 0; k2 < 8; ++k2)
                sb[k2] = (e0 + k2 < cntn) ? csr_l[ex + e0 + k2] : -1;
#pragma unroll
            for (int k2 = 0; k2 < 8; ++k2) {
                if (sb[k2] >= 0) {
                    int s = sb[k2];
                    float w = disl[s] * dn;
                    float4 r0 = x4[s * 2], r1 = x4[s * 2 + 1];
                    aX[0] += r0.x * w; aX[1] += r0.y * w; aX[2] += r0.z * w; aX[3] += r0.w * w;
                    aX[4] += r1.x * w; aX[5] += r1.y * w; aX[6] += r1.z * w; aX[7] += r1.w * w;
                }
            }
        }
        // phase 1: h1 = relu(aX @ W1 + b1) — block-uniform weight loads
        float h1r[64];
        {
            const float4* b14 = reinterpret_cast<const float4*>(b1);
#pragma unroll
            for (int f4 = 0; f4 < 16; ++f4) {
                float4 b = b14[f4];
                h1r[4 * f4 + 0] = b.x; h1r[4 * f4 + 1] = b.y;
                h1r[4 * f4 + 2] = b.z; h1r[4 * f4 + 3] = b.w;
            }
            const float4* W14 = reinterpret_cast<const float4*>(W1);
#pragma unroll
            for (int k2 = 0; k2 < 8; ++k2) {
                float hk = aX[k2];
#pragma unroll
                for (int f4 = 0; f4 < 16; ++f4) {
                    float4 w = W14[k2 * 16 + f4];
                    h1r[4 * f4 + 0] += hk * w.x; h1r[4 * f4 + 1] += hk * w.y;
                    h1r[4 * f4 + 2] += hk * w.z; h1r[4 * f4 + 3] += hk * w.w;
                }
            }
#pragma unroll
            for (int f = 0; f < 64; ++f) h1r[f] = fmaxf(h1r[f], 0.f);
        }
        // phase 2: t2 = h1 @ W2 (fp8 out), two 32-feature halves; hf is a LOOP
        // variable (block-uniform W2 addresses -> s_load path; R4 lesson)
        uint4 oh[2][2];
        {
            const float4* W24 = reinterpret_cast<const float4*>(W2);
#pragma unroll
            for (int hf = 0; hf < 2; ++hf) {
                float acch[32];
#pragma unroll
                for (int f = 0; f < 32; ++f) acch[f] = 0.f;
#pragma unroll
                for (int k2 = 0; k2 < 64; ++k2) {
                    float hk = h1r[k2];
#pragma unroll
                    for (int f4 = 0; f4 < 8; ++f4) {
                        float4 w = W24[k2 * 16 + hf * 8 + f4];
                        acch[4 * f4 + 0] += hk * w.x; acch[4 * f4 + 1] += hk * w.y;
                        acch[4 * f4 + 2] += hk * w.z; acch[4 * f4 + 3] += hk * w.w;
                    }
                }
                oh[hf][0].x = fp8_pack4(acch[0],  acch[1],  acch[2],  acch[3]);
                oh[hf][0].y = fp8_pack4(acch[4],  acch[5],  acch[6],  acch[7]);
                oh[hf][0].z = fp8_pack4(acch[8],  acch[9],  acch[10], acch[11]);
                oh[hf][0].w = fp8_pack4(acch[12], acch[13], acch[14], acch[15]);
                oh[hf][1].x = fp8_pack4(acch[16], acch[17], acch[18], acch[19]);
                oh[hf][1].y = fp8_pack4(acch[20], acch[21], acch[22], acch[23]);
                oh[hf][1].z = fp8_pack4(acch[24], acch[25], acch[26], acch[27]);
                oh[hf][1].w = fp8_pack4(acch[28], acch[29], acch[30], acch[31]);
            }
        }
        uint4* op = reinterpret_cast<uint4*>(t2f + ((size_t)g * Nn + n) * 64);
        op[0] = oh[0][0]; op[1] = oh[0][1]; op[2] = oh[1][0]; op[3] = oh[1][1];
    }
}

// ---- K3: LDS-staged aggregation of t2 (fp8) + relu + mean-pool.
// 1-deep et prefetch (R9): issue et[e+1] before the ~112-inst edge body.
__global__ void __launch_bounds__(1024, 1)
k_aggF(const unsigned char* __restrict__ t2f, const unsigned* __restrict__ ellT,
       const int* __restrict__ cntS, const int* __restrict__ ordS,
       const int* __restrict__ startA, const int* __restrict__ csr,
       const float* __restrict__ dis, const float* __restrict__ bias,
       float* __restrict__ emb) {
    __shared__ uint4 stage[Nn * 5];     // 160,000 B; row s at stage[s*5 .. s*5+3]
    int i = blockIdx.x;                 // 240 = 8 xcd * 15 frames * 2 halves
    int xcd = i & 7;
    int j = i >> 3;                     // 0..29
    int g = xcd * 15 + (j >> 1);
    int half = j & 1;
    int tid = threadIdx.x;              // 0..1023
    int w = tid >> 6, lane = tid & 63;
    // stage entire frame t2 (fp8) into LDS with padded stride
    {
        const uint4* src = reinterpret_cast<const uint4*>(t2f + (size_t)g * Nn * 64);
        for (int it = tid; it < Nn * 4; it += 1024)
            stage[(it >> 2) * 5 + (it & 3)] = src[it];
    }
    __syncthreads();
#define ROWFMA(dw, base) { float o_[4]; fp8x4_dec(dw, o_); \
    acc[base + 0] += o_[0] * wt; acc[base + 1] += o_[1] * wt; \
    acc[base + 2] += o_[2] * wt; acc[base + 3] += o_[3] * wt; }
#define EDGEFMA(s, wt) { \
    uint4 r0 = stage[(s) * 5], r1 = stage[(s) * 5 + 1]; \
    uint4 r2 = stage[(s) * 5 + 2], r3 = stage[(s) * 5 + 3]; \
    ROWFMA(r0.x, 0)  ROWFMA(r0.y, 4)  ROWFMA(r0.z, 8)  ROWFMA(r0.w, 12) \
    ROWFMA(r1.x, 16) ROWFMA(r1.y, 20) ROWFMA(r1.z, 24) ROWFMA(r1.w, 28) \
    ROWFMA(r2.x, 32) ROWFMA(r2.y, 36) ROWFMA(r2.z, 40) ROWFMA(r2.w, 44) \
    ROWFMA(r3.x, 48) ROWFMA(r3.y, 52) ROWFMA(r3.z, 56) ROWFMA(r3.w, 60) }
    int po = w * 64 + lane;             // 0..1023
    int p = half * 1000 + po;           // sorted position
    bool valid = (po < 1000);
    size_t gp = (size_t)g * Nn + (valid ? p : 0);
    int cnt = valid ? cntS[gp] : 0;
    int myc = valid ? (min(cnt, TSLOT - 1) + 1) : 0;
    float acc[64];
#pragma unroll
    for (int k = 0; k < 64; ++k) acc[k] = 0.f;
    const unsigned* et = ellT + (size_t)g * TSLOT * Nn + (valid ? p : 0);
    unsigned u_cur = (0 < myc) ? et[0] : 0u;
    for (int e = 0; e < TSLOT; ++e) {
        if (!__any(e < myc)) break;
        unsigned u_nxt = ((e + 1) < TSLOT && (e + 1) < myc)
                             ? et[(size_t)(e + 1) * Nn] : 0u;   // issued early
        if (e < myc) {
            float wt = __uint_as_float(u_cur & 0xffff0000u);
            int s = u_cur & 0xffffu;
            EDGEFMA(s, wt)
        }
        u_cur = u_nxt;
    }
    if (cnt > TSLOT - 1) {              // rare overflow (deg > 47)
        int n = ordS[gp];
        size_t gn = (size_t)g * Nn + n;
        float dn = dis[gn];
        int start = startA[gn];
        const float* dsg = dis + (size_t)g * Nn;
        for (int e = TSLOT - 1; e < cnt; ++e) {
            int s = csr[start + e];
            float wt = dsg[s] * dn;
            EDGEFMA(s, wt)
        }
    }
#undef EDGEFMA
#undef ROWFMA
    // bias + relu + per-feature butterfly pool over the wave's 64 positions
    float pool = 0.f;
#pragma unroll
    for (int k = 0; k < 64; ++k) {
        float v = valid ? fmaxf(acc[k] + bias[k], 0.f) : 0.f;
        v += __shfl_xor(v, 1);  v += __shfl_xor(v, 2);  v += __shfl_xor(v, 4);
        v += __shfl_xor(v, 8);  v += __shfl_xor(v, 16); v += __shfl_xor(v, 32);
        if (lane == k) pool = v;
    }
    atomicAdd(&emb[g * 64 + lane], pool * (1.0f / Nn));
}

// ---- K5: sequential GRU over T with FUSED gi precompute (k_gi removed).
__global__ void __launch_bounds__(768, 1)
k_gru_seq(const float* __restrict__ emb, const float* __restrict__ W_ih,
          const float* __restrict__ b_ih, const float* __restrict__ W_hh,
          const float* __restrict__ b_hh, const float* __restrict__ fc_w,
          const float* __restrict__ fc_b, float* __restrict__ out) {
    __shared__ float h[Fg];
    __shared__ float part[768];
    __shared__ float embs[Tt][64];       // 7.7 KB
    __shared__ float pgi[Tt][768];       // 92 KB: gi half-dots
    int b = blockIdx.x;                  // batch
    int tid = threadIdx.x;               // 0..767
    int row = tid >> 1;                  // gate-row 0..383
    int half = tid & 1;                  // which 64-slice of k
    float w[64];
    const float* wr = W_hh + (size_t)row * Fg + half * 64;
#pragma unroll
    for (int i = 0; i < 64; ++i) w[i] = wr[i];
    float wih[32];
    const float* wir = W_ih + (size_t)row * 64 + half * 32;
#pragma unroll
    for (int i = 0; i < 32; ++i) wih[i] = wir[i];
    // stage emb rows for this batch
    for (int it = tid; it < Tt * 64; it += 768)
        embs[it >> 6][it & 63] = emb[((size_t)b * Tt) * 64 + it];
    if (tid < Fg) h[tid] = 0.f;
    __syncthreads();
    // precompute gi half-dots for all timesteps (independent per thread)
    for (int t = 0; t < Tt; ++t) {
        const float* e = &embs[t][half * 32];
        float a0 = 0.f, a1 = 0.f, a2 = 0.f, a3 = 0.f;
#pragma unroll
        for (int i = 0; i < 8; ++i) {
            a0 += wih[4 * i + 0] * e[4 * i + 0];
            a1 += wih[4 * i + 1] * e[4 * i + 1];
            a2 += wih[4 * i + 2] * e[4 * i + 2];
            a3 += wih[4 * i + 3] * e[4 * i + 3];
        }
        pgi[t][tid] = (a0 + a1) + (a2 + a3);
    }
    __syncthreads();
    for (int t = 0; t < Tt; ++t) {
        const float* hh = &h[half * 64];
        float a0 = 0.f, a1 = 0.f, a2 = 0.f, a3 = 0.f;
#pragma unroll
        for (int i = 0; i < 16; ++i) {
            a0 += w[4 * i + 0] * hh[4 * i + 0];
            a1 += w[4 * i + 1] * hh[4 * i + 1];
            a2 += w[4 * i + 2] * hh[4 * i + 2];
            a3 += w[4 * i + 3] * hh[4 * i + 3];
        }
        part[tid] = (a0 + a1) + (a2 + a3);
        __syncthreads();
        if (tid < Fg) {
            int j = tid;
            float hr = b_hh[j]       + part[2 * j]           + part[2 * j + 1];
            float hz = b_hh[128 + j] + part[2 * (128 + j)]   + part[2 * (128 + j) + 1];
            float hn = b_hh[256 + j] + part[2 * (256 + j)]   + part[2 * (256 + j) + 1];
            float gr = b_ih[j]       + pgi[t][2 * j]         + pgi[t][2 * j + 1];
            float gz = b_ih[128 + j] + pgi[t][2 * (128 + j)] + pgi[t][2 * (128 + j) + 1];
            float gn = b_ih[256 + j] + pgi[t][2 * (256 + j)] + pgi[t][2 * (256 + j) + 1];
            float r  = 1.f / (1.f + expf(-(gr + hr)));
            float z  = 1.f / (1.f + expf(-(gz + hz)));
            float nn = tanhf(gn + r * hn);
            h[j] = (1.f - z) * nn + z * h[j];
        }
        __syncthreads();
    }
    if (tid < 2) {
        float acc = fc_b[tid];
        for (int k = 0; k < Fg; ++k) acc += fc_w[tid * Fg + k] * h[k];
        out[b * 2 + tid] = acc;
    }
}

// ----------------------------------------------------------------- launcher
extern "C" void kernel_launch(void* const* d_in, const int* in_sizes, int n_in,
                              void* d_out, int out_size, void* d_ws, size_t ws_size,
                              hipStream_t stream) {
    const float* x     = (const float*)d_in[0];
    const int*   ei    = (const int*)  d_in[1];
    const float* W1    = (const float*)d_in[2];
    const float* b1    = (const float*)d_in[3];
    const float* W2    = (const float*)d_in[4];
    const float* b2    = (const float*)d_in[5];
    const float* W_ih  = (const float*)d_in[6];
    const float* W_hh  = (const float*)d_in[7];
    const float* b_ih  = (const float*)d_in[8];
    const float* b_hh  = (const float*)d_in[9];
    const float* fc_w  = (const float*)d_in[10];
    const float* fc_b  = (const float*)d_in[11];
    float* out = (float*)d_out;

    char* ws = (char*)d_ws;
    size_t off = 0;
    auto alloc = [&](size_t bytes) -> void* {
        void* p = ws + off;
        off = (off + bytes + 255) & ~(size_t)255;
        return p;
    };
    float*    dis    = (float*)   alloc((size_t)G * Nn * 4);
    int*      startA = (int*)     alloc((size_t)G * Nn * 4);
    int*      cntS   = (int*)     alloc((size_t)G * Nn * 4);
    int*      ordS   = (int*)     alloc((size_t)G * Nn * 4);
    int*      csr    = (int*)     alloc((size_t)G * 4 * QCAP * 4);
    unsigned* ellT   = (unsigned*)alloc((size_t)G * TSLOT * Nn * 4);
    unsigned char* t2f = (unsigned char*)alloc((size_t)G * Nn * 64);
    float*    emb    = (float*)   alloc((size_t)G * 64 * 4);
    (void)ws_size; (void)in_sizes; (void)n_in; (void)out_size;

    hipLaunchKernelGGL(k_bfuse,   dim3(2 * G), dim3(1024), 0, stream,
                       ei, x, W1, b1, W2, dis, startA, csr, ellT, cntS, ordS, emb, t2f);
    hipLaunchKernelGGL(k_aggF,    dim3(240), dim3(1024), 0, stream, t2f, ellT, cntS, ordS, startA, csr, dis, b2, emb);
    hipLaunchKernelGGL(k_gru_seq, dim3(Bb), dim3(768), 0, stream, emb, W_ih, b_ih, W_hh, b_hh, fc_w, fc_b, out);
}